// Round 1
// baseline (3384.789 us; speedup 1.0000x reference)
//
#include <hip/hip_runtime.h>
#include <cstdint>
#include <cmath>

// Shapes (fixed by the problem)
#define LQ   999      // conv output length (8000-16)/8+1
#define BLQ  1998     // BATCH * LQ
#define NCH  256      // encoder channels
#define NLTOT 255744  // NCH*LQ (per batch)

// -------------------- encoder conv + relu + groupnorm partial sums --------------------
__global__ __launch_bounds__(256) void k_enc(const float* __restrict__ mix,
                                             const float* __restrict__ ew,
                                             float* __restrict__ mw,
                                             float* __restrict__ stats) {
  int t = threadIdx.x;
  int b = blockIdx.x >= LQ;                 // 999 blocks per batch, exact
  int rem = (blockIdx.x - b * LQ) * 256 + t;
  int n = rem / LQ;
  int l = rem - n * LQ;
  const float* mp = mix + b * 8000 + l * 8;
  const float* wp = ew + n * 16;
  float acc = 0.f;
#pragma unroll
  for (int k = 0; k < 16; ++k) acc += mp[k] * wp[k];
  float v = fmaxf(acc, 0.f);
  mw[(b * NCH + n) * LQ + l] = v;
  // block reduction for mean/var
  float s1 = v, s2 = v * v;
#pragma unroll
  for (int off = 32; off >= 1; off >>= 1) {
    s1 += __shfl_xor(s1, off, 64);
    s2 += __shfl_xor(s2, off, 64);
  }
  __shared__ float r1[4], r2[4];
  int wv = t >> 6, lane = t & 63;
  if (lane == 0) { r1[wv] = s1; r2[wv] = s2; }
  __syncthreads();
  if (t == 0) {
    atomicAdd(&stats[b * 2 + 0], r1[0] + r1[1] + r1[2] + r1[3]);
    atomicAdd(&stats[b * 2 + 1], r2[0] + r2[1] + r2[2] + r2[3]);
  }
}

__global__ void k_stats(float* stats) {
  int t = threadIdx.x;
  if (t < 2) {
    float s = stats[t * 2 + 0], q = stats[t * 2 + 1];
    float mu = s / (float)NLTOT;
    float var = q / (float)NLTOT - mu * mu;
    stats[4 + t * 2 + 0] = mu;
    stats[4 + t * 2 + 1] = 1.f / sqrtf(var + 1e-5f);
  }
}

// Fold groupnorm affine into bottleneck GEMM: w2[o][n] = bot_w*gn_w,
// cc[b][o] = bot_b + sum(bot_w*gn_b) - mu_b*inv_b*sum(bot_w*gn_w)
__global__ __launch_bounds__(256) void k_prep(const float* __restrict__ bw,
                                              const float* __restrict__ gw,
                                              const float* __restrict__ gb,
                                              const float* __restrict__ bb,
                                              const float* __restrict__ stats,
                                              float* __restrict__ w2,
                                              float* __restrict__ cc) {
  int o = blockIdx.x, n = threadIdx.x;
  float bwv = bw[o * 256 + n];
  float w2v = bwv * gw[n];
  w2[o * 256 + n] = w2v;
  float s1 = bwv * gb[n], s2 = w2v;
#pragma unroll
  for (int off = 32; off >= 1; off >>= 1) {
    s1 += __shfl_xor(s1, off, 64);
    s2 += __shfl_xor(s2, off, 64);
  }
  __shared__ float r1[4], r2[4];
  int wv = n >> 6, lane = n & 63;
  if (lane == 0) { r1[wv] = s1; r2[wv] = s2; }
  __syncthreads();
  if (n == 0) {
    float a1 = r1[0] + r1[1] + r1[2] + r1[3];
    float a2 = r2[0] + r2[1] + r2[2] + r2[3];
    for (int b = 0; b < 2; ++b)
      cc[b * 256 + o] = bb[o] + a1 - stats[4 + b * 2] * stats[5 + b * 2] * a2;
  }
}

// -------------------- rmsnorm over last dim (256) --------------------
__global__ __launch_bounds__(256) void k_rms(const float* __restrict__ x,
                                             const float* __restrict__ w,
                                             float* __restrict__ out) {
  int t = threadIdx.x;
  int row = blockIdx.x * 4 + (t >> 6);
  int lane = t & 63;
  if (row >= BLQ) return;
  float4 v = *(const float4*)&x[row * 256 + lane * 4];
  float ss = v.x * v.x + v.y * v.y + v.z * v.z + v.w * v.w;
#pragma unroll
  for (int off = 32; off >= 1; off >>= 1) ss += __shfl_xor(ss, off, 64);
  float r = 1.f / sqrtf(ss * (1.f / 256.f) + 1e-5f);
  float4 wv = *(const float4*)&w[lane * 4];
  float4 o;
  o.x = v.x * wv.x * r; o.y = v.y * wv.y * r;
  o.z = v.z * wv.z * r; o.w = v.w * wv.w * r;
  *(float4*)&out[row * 256 + lane * 4] = o;
}

// -------------------- generic 64x64 tiled fp32 GEMM, C = A * B^T (+mode epilogue) ----
// MODE 0: bottleneck  A=mw (col-gather + norm fold), B=w2, C=x (256)
// MODE 1: in-proj     A=xn (row-major K=256),  B=in_w[i] (2048x256), C=xz (2048)
// MODE 2: out-proj    A=g (dir-concat K=1024), B=out_w[i],           C+=  (256)
// MODE 3: masks       A=xn (row-major),        B=mask_w, epilogue relu*mw -> masked
// MODE 4: xproj       A=xc (per-dir, K=512),   B=xproj_w[i,dir] (48x512), C=xdbl (48)
template <int MODE>
__global__ __launch_bounds__(256) void gemm64(const float* __restrict__ A,
                                              const float* __restrict__ Bw,
                                              float* __restrict__ C,
                                              const float* __restrict__ aux1,
                                              const float* __restrict__ aux2,
                                              int M, int K,
                                              int aDS, int bDS, int cDS) {
  if (MODE == 4) {
    A += (size_t)blockIdx.z * aDS;
    Bw += (size_t)blockIdx.z * bDS;
    C += (size_t)blockIdx.z * cDS;
  }
  __shared__ float As[16][68];
  __shared__ float Bs[16][68];
  int t = threadIdx.x;
  int m0 = blockIdx.x * 64, n0 = blockIdx.y * 64;
  int tx = t & 15, ty = t >> 4;
  float acc[4][4] = {};
  for (int kk = 0; kk < K; kk += 16) {
    // ---- A tile ----
    if (MODE == 0) {
#pragma unroll
      for (int j = 0; j < 4; ++j) {
        int e = t + 256 * j;
        int m_ = e & 63, k_ = e >> 6;
        int m = m0 + m_;
        float v = 0.f;
        if (m < M) {
          int bb = m >= LQ;
          int l = m - bb * LQ;
          v = A[(size_t)((bb << 8) + kk + k_) * LQ + l];
        }
        As[k_][m_] = v;
      }
    } else {
      int m_ = t >> 2, k4 = (t & 3) * 4;
      int m = m0 + m_;
      float4 v = make_float4(0.f, 0.f, 0.f, 0.f);
      if (m < M) {
        if (MODE == 2) {
          int k = kk + k4;
          v = *(const float4*)&A[(size_t)(k >> 9) * aDS + (size_t)m * 512 + (k & 511)];
        } else {
          v = *(const float4*)&A[(size_t)m * K + kk + k4];
        }
      }
      As[k4 + 0][m_] = v.x; As[k4 + 1][m_] = v.y;
      As[k4 + 2][m_] = v.z; As[k4 + 3][m_] = v.w;
    }
    // ---- B tile ----
    {
      int n_ = t >> 2, k4 = (t & 3) * 4;
      int n = n0 + n_;
      float4 v = make_float4(0.f, 0.f, 0.f, 0.f);
      if (MODE != 4 || n_ < 48) {
        if (MODE == 2) {
          int k = kk + k4;
          v = *(const float4*)&Bw[(size_t)(k >> 9) * bDS + (size_t)n * 512 + (k & 511)];
        } else {
          v = *(const float4*)&Bw[(size_t)n * K + kk + k4];
        }
      }
      Bs[k4 + 0][n_] = v.x; Bs[k4 + 1][n_] = v.y;
      Bs[k4 + 2][n_] = v.z; Bs[k4 + 3][n_] = v.w;
    }
    __syncthreads();
#pragma unroll
    for (int k = 0; k < 16; ++k) {
      float4 av = *(const float4*)&As[k][ty * 4];
      float4 bv = *(const float4*)&Bs[k][tx * 4];
      acc[0][0] += av.x * bv.x; acc[0][1] += av.x * bv.y; acc[0][2] += av.x * bv.z; acc[0][3] += av.x * bv.w;
      acc[1][0] += av.y * bv.x; acc[1][1] += av.y * bv.y; acc[1][2] += av.y * bv.z; acc[1][3] += av.y * bv.w;
      acc[2][0] += av.z * bv.x; acc[2][1] += av.z * bv.y; acc[2][2] += av.z * bv.z; acc[2][3] += av.z * bv.w;
      acc[3][0] += av.w * bv.x; acc[3][1] += av.w * bv.y; acc[3][2] += av.w * bv.z; acc[3][3] += av.w * bv.w;
    }
    __syncthreads();
  }
  // ---- epilogue ----
#pragma unroll
  for (int i = 0; i < 4; ++i) {
    int m = m0 + ty * 4 + i;
    if (m < M) {
      int n = n0 + tx * 4;
      if (MODE == 0) {
        int bb = m >= LQ;
        float invb = aux1[5 + bb * 2];
        float4 cv = *(const float4*)&aux2[(bb << 8) + n];
        float4 o;
        o.x = acc[i][0] * invb + cv.x; o.y = acc[i][1] * invb + cv.y;
        o.z = acc[i][2] * invb + cv.z; o.w = acc[i][3] * invb + cv.w;
        *(float4*)&C[(size_t)m * 256 + n] = o;
      } else if (MODE == 1) {
        float4 o = {acc[i][0], acc[i][1], acc[i][2], acc[i][3]};
        *(float4*)&C[(size_t)m * 2048 + n] = o;
      } else if (MODE == 2) {
        float4 old = *(const float4*)&C[(size_t)m * 256 + n];
        old.x += acc[i][0]; old.y += acc[i][1];
        old.z += acc[i][2]; old.w += acc[i][3];
        *(float4*)&C[(size_t)m * 256 + n] = old;
      } else if (MODE == 3) {
        int bb = m >= LQ;
        int l = m - bb * LQ;
#pragma unroll
        for (int j = 0; j < 4; ++j) {
          int nc = n + j;
          float v = fmaxf(acc[i][j] + aux1[nc], 0.f);
          size_t idx = (size_t)((bb << 8) + nc) * LQ + l;
          C[idx] = v * aux2[idx];
        }
      } else {  // MODE 4
#pragma unroll
        for (int j = 0; j < 4; ++j) {
          int nc = n + j;
          if (nc < 48) C[(size_t)m * 48 + nc] = acc[i][j];
        }
      }
    }
  }
}

// -------------------- depthwise causal / anti-causal conv + silu --------------------
__global__ __launch_bounds__(256) void k_conv(const float* __restrict__ xz,
                                              const float* __restrict__ cwAll,
                                              const float* __restrict__ cbAll,
                                              float* __restrict__ xc, int blk) {
  int dir = blockIdx.y;
  int flat = blockIdx.x * 256 + threadIdx.x;   // exactly BLQ*512
  int d = flat & 511, bl = flat >> 9;
  int bb = bl >= LQ;
  int l = bl - bb * LQ;
  int w = blk * 2 + dir;
  const float* cw = cwAll + (size_t)(w * 512 + d) * 4;
  float acc = cbAll[w * 512 + d];
  int zoff = dir * 1024 + d;
#pragma unroll
  for (int j = 0; j < 4; ++j) {
    int ls = (dir == 0) ? (l - 3 + j) : (l + 3 - j);
    if (ls >= 0 && ls < LQ) acc += xz[(size_t)(bb * LQ + ls) * 2048 + zoff] * cw[j];
  }
  float sg = acc / (1.f + __expf(-acc));
  xc[(size_t)(dir * BLQ + bl) * 512 + d] = sg;
}

// -------------------- dt projection (K=16) + softplus --------------------
__global__ __launch_bounds__(256) void k_dt(const float* __restrict__ xdbl,
                                            const float* __restrict__ dtwAll,
                                            const float* __restrict__ dtbAll,
                                            float* __restrict__ dtg, int blk) {
  int dir = blockIdx.y;
  int flat = blockIdx.x * 256 + threadIdx.x;
  int d = flat & 511, bl = flat >> 9;
  int w = blk * 2 + dir;
  const float* xd = xdbl + (size_t)(dir * BLQ + bl) * 48;
  const float* Wp = dtwAll + (size_t)(w * 512 + d) * 16;
  float acc = dtbAll[w * 512 + d];
#pragma unroll
  for (int q = 0; q < 16; ++q) acc += xd[q] * Wp[q];
  float sp = fmaxf(acc, 0.f) + log1pf(expf(-fabsf(acc)));
  dtg[(size_t)(dir * BLQ + bl) * 512 + d] = sp;
}

// -------------------- selective scan (+D term, + silu(z) gating) --------------------
// 16 lanes per (b,d) channel: lane s holds state s. 8-step register prefetch,
// staggered keep (lane c&15 keeps step c), flush every 16 steps.
__global__ __launch_bounds__(256) void k_scan(const float* __restrict__ dtg,
                                              const float* __restrict__ xc,
                                              const float* __restrict__ xdbl,
                                              const float* __restrict__ xz,
                                              const float* __restrict__ alog,
                                              const float* __restrict__ dmat,
                                              float* __restrict__ g, int blk) {
  int t = threadIdx.x;
  int dir = blockIdx.z, b = blockIdx.y;
  int s = t & 15, grp = t >> 4;
  int d = blockIdx.x * 16 + grp;
  int w = blk * 2 + dir;
  float a2 = -__expf(alog[(size_t)(w * 512 + d) * 16 + s]) * 1.44269504f;  // A*log2(e)
  float Dd = dmat[w * 512 + d];
  const float* dtp = dtg + (size_t)dir * BLQ * 512;
  const float* xcp = xc + (size_t)dir * BLQ * 512;
  const float* xdp = xdbl + (size_t)dir * BLQ * 48;
  const float* zp = xz + dir * 1024 + 512 + d;
  float* gp = g + (size_t)dir * BLQ * 512;
  int b999 = b * LQ;

  float h = 0.f, keepP = 0.f, keepXv = 0.f;
  int keepBl = 0;
  float cd[8], cx[8], cB[8], cC[8];
  float nd[8], nx[8], nB[8], nC[8];

  auto LD = [&](int c, float& od, float& ox, float& oB, float& oC) {
    if (c < LQ) {
      int l = dir ? (LQ - 1 - c) : c;
      int bl = b999 + l;
      od = dtp[(size_t)bl * 512 + d];
      ox = xcp[(size_t)bl * 512 + d];
      oB = xdp[(size_t)bl * 48 + 16 + s];
      oC = xdp[(size_t)bl * 48 + 32 + s];
    } else {
      od = 0.f; ox = 0.f; oB = 0.f; oC = 0.f;
    }
  };

#pragma unroll
  for (int j = 0; j < 8; ++j) LD(j, cd[j], cx[j], cB[j], cC[j]);

  for (int c0 = 0; c0 < LQ; c0 += 8) {
#pragma unroll
    for (int j = 0; j < 8; ++j) LD(c0 + 8 + j, nd[j], nx[j], nB[j], nC[j]);
#pragma unroll
    for (int j = 0; j < 8; ++j) {
      int c = c0 + j;
      if (c < LQ) {
        float dA = exp2f(cd[j] * a2);
        h = dA * h + (cd[j] * cx[j]) * cB[j];
        float p = h * cC[j];
        p += __shfl_xor(p, 1, 16);
        p += __shfl_xor(p, 2, 16);
        p += __shfl_xor(p, 4, 16);
        p += __shfl_xor(p, 8, 16);
        int l = dir ? (LQ - 1 - c) : c;
        int bl = b999 + l;
        if ((c & 15) == s) { keepP = p; keepXv = cx[j]; keepBl = bl; }
        if ((c & 15) == 15 || c == LQ - 1) {
          int lim = c & 15;
          if (s <= lim) {
            float zv = zp[(size_t)keepBl * 2048];
            float sig = 1.f / (1.f + __expf(-zv));
            gp[(size_t)keepBl * 512 + d] = (keepP + keepXv * Dd) * (zv * sig);
          }
        }
      }
      cd[j] = nd[j]; cx[j] = nx[j]; cB[j] = nB[j]; cC[j] = nC[j];
    }
  }
}

// -------------------- transposed conv decoder --------------------
__global__ __launch_bounds__(256) void k_dec(const float* __restrict__ masked,
                                             const float* __restrict__ dw,
                                             float* __restrict__ out) {
  int idx = blockIdx.x * 256 + threadIdx.x;
  if (idx >= 16000) return;
  int b = idx >= 8000;
  int tt = idx - b * 8000;
  int j0 = tt & 7, l0 = tt >> 3;
  const float* mp = masked + (size_t)b * NCH * LQ;
  bool v0 = l0 <= LQ - 1;
  bool v1 = l0 >= 1;
  float acc = 0.f;
#pragma unroll 4
  for (int n = 0; n < 256; ++n) {
    const float* col = mp + (size_t)n * LQ;
    const float* wn = dw + n * 16;
    if (v0) acc += col[l0] * wn[j0];
    if (v1) acc += col[l0 - 1] * wn[j0 + 8];
  }
  out[idx] = acc;
}

// ==================== launch ====================
extern "C" void kernel_launch(void* const* d_in, const int* in_sizes, int n_in,
                              void* d_out, int out_size, void* d_ws, size_t ws_size,
                              hipStream_t stream) {
  const float* mixture = (const float*)d_in[0];
  const float* enc_w = (const float*)d_in[1];
  const float* dec_w = (const float*)d_in[2];
  const float* gn_w = (const float*)d_in[3];
  const float* gn_b = (const float*)d_in[4];
  const float* bot_w = (const float*)d_in[5];
  const float* bot_b = (const float*)d_in[6];
  const float* blk_norm_w = (const float*)d_in[7];
  const float* in_w = (const float*)d_in[8];
  const float* conv_w = (const float*)d_in[9];
  const float* conv_b = (const float*)d_in[10];
  const float* xproj_w = (const float*)d_in[11];
  const float* dt_w = (const float*)d_in[12];
  const float* dt_b = (const float*)d_in[13];
  const float* A_log = (const float*)d_in[14];
  const float* Dmat = (const float*)d_in[15];
  const float* out_w = (const float*)d_in[16];
  const float* normf_w = (const float*)d_in[17];
  const float* mask_w = (const float*)d_in[18];
  const float* mask_b = (const float*)d_in[19];
  float* outp = (float*)d_out;

  float* W = (float*)d_ws;
  size_t off = 0;
  auto alloc = [&](size_t n) {
    float* p = W + off;
    off += (n + 255) & ~(size_t)255;
    return p;
  };
  float* stats = alloc(8);          // [sum0,sq0,sum1,sq1, mu0,inv0, mu1,inv1]
  float* w2 = alloc(65536);
  float* cc = alloc(512);
  float* mw = alloc(511488);        // [b][n][l]
  float* x = alloc(511488);         // [bl][256]
  float* xn = alloc(511488);
  float* xzb = alloc(4091904);      // [bl][2048]
  float* xcb = alloc(2045952);      // [dir][bl][512]
  float* xdblb = alloc(191808);     // [dir][bl][48]
  float* dtgb = alloc(2045952);     // [dir][bl][512]
  float* gb = alloc(2045952);       // [dir][bl][512]  gated scan output
  float* maskedb = alloc(511488);   // [b][n][l]

  hipMemsetAsync(stats, 0, 32, stream);
  k_enc<<<1998, 256, 0, stream>>>(mixture, enc_w, mw, stats);
  k_stats<<<1, 64, 0, stream>>>(stats);
  k_prep<<<256, 256, 0, stream>>>(bot_w, gn_w, gn_b, bot_b, stats, w2, cc);
  gemm64<0><<<dim3(32, 4, 1), 256, 0, stream>>>(mw, w2, x, stats, cc, BLQ, 256, 0, 0, 0);

  for (int i = 0; i < 8; ++i) {
    k_rms<<<500, 256, 0, stream>>>(x, blk_norm_w + i * 256, xn);
    gemm64<1><<<dim3(32, 32, 1), 256, 0, stream>>>(
        xn, in_w + (size_t)i * 2 * 1024 * 256, xzb, nullptr, nullptr, BLQ, 256, 0, 0, 0);
    k_conv<<<dim3(3996, 2, 1), 256, 0, stream>>>(xzb, conv_w, conv_b, xcb, i);
    gemm64<4><<<dim3(32, 1, 2), 256, 0, stream>>>(
        xcb, xproj_w + (size_t)i * 2 * 48 * 512, xdblb, nullptr, nullptr, BLQ, 512,
        BLQ * 512, 48 * 512, BLQ * 48);
    k_dt<<<dim3(3996, 2, 1), 256, 0, stream>>>(xdblb, dt_w, dt_b, dtgb, i);
    k_scan<<<dim3(32, 2, 2), 256, 0, stream>>>(dtgb, xcb, xdblb, xzb, A_log, Dmat, gb, i);
    gemm64<2><<<dim3(32, 4, 1), 256, 0, stream>>>(
        gb, out_w + (size_t)i * 2 * 256 * 512, x, nullptr, nullptr, BLQ, 1024,
        BLQ * 512, 256 * 512, 0);
  }

  k_rms<<<500, 256, 0, stream>>>(x, normf_w, xn);
  gemm64<3><<<dim3(32, 4, 1), 256, 0, stream>>>(xn, mask_w, maskedb, mask_b, mw, BLQ, 256, 0, 0, 0);
  k_dec<<<63, 256, 0, stream>>>(maskedb, dec_w, outp);
}

// Round 3
// 2606.334 us; speedup vs baseline: 1.2987x; 1.2987x over previous
//
#include <hip/hip_runtime.h>
#include <cstdint>
#include <cmath>

// Shapes (fixed by the problem)
#define LQ   999      // conv output length (8000-16)/8+1
#define BLQ  1998     // BATCH * LQ
#define NCH  256      // encoder channels
#define NLTOT 255744  // NCH*LQ (per batch)
#define NCHK 16       // scan chunks per sequence
#define CHL  64       // chunk length (16*64=1024 >= 999)

// -------------------- encoder conv + relu + groupnorm partial sums --------------------
__global__ __launch_bounds__(256) void k_enc(const float* __restrict__ mix,
                                             const float* __restrict__ ew,
                                             float* __restrict__ mw,
                                             float* __restrict__ stats) {
  int t = threadIdx.x;
  int b = blockIdx.x >= LQ;                 // 999 blocks per batch, exact
  int rem = (blockIdx.x - b * LQ) * 256 + t;
  int n = rem / LQ;
  int l = rem - n * LQ;
  const float* mp = mix + b * 8000 + l * 8;
  const float* wp = ew + n * 16;
  float acc = 0.f;
#pragma unroll
  for (int k = 0; k < 16; ++k) acc += mp[k] * wp[k];
  float v = fmaxf(acc, 0.f);
  mw[(b * NCH + n) * LQ + l] = v;
  // block reduction for mean/var
  float s1 = v, s2 = v * v;
#pragma unroll
  for (int off = 32; off >= 1; off >>= 1) {
    s1 += __shfl_xor(s1, off, 64);
    s2 += __shfl_xor(s2, off, 64);
  }
  __shared__ float r1[4], r2[4];
  int wv = t >> 6, lane = t & 63;
  if (lane == 0) { r1[wv] = s1; r2[wv] = s2; }
  __syncthreads();
  if (t == 0) {
    atomicAdd(&stats[b * 2 + 0], r1[0] + r1[1] + r1[2] + r1[3]);
    atomicAdd(&stats[b * 2 + 1], r2[0] + r2[1] + r2[2] + r2[3]);
  }
}

__global__ void k_stats(float* stats) {
  int t = threadIdx.x;
  if (t < 2) {
    float s = stats[t * 2 + 0], q = stats[t * 2 + 1];
    float mu = s / (float)NLTOT;
    float var = q / (float)NLTOT - mu * mu;
    stats[4 + t * 2 + 0] = mu;
    stats[4 + t * 2 + 1] = 1.f / sqrtf(var + 1e-5f);
  }
}

// Fold groupnorm affine into bottleneck GEMM: w2[o][n] = bot_w*gn_w,
// cc[b][o] = bot_b + sum(bot_w*gn_b) - mu_b*inv_b*sum(bot_w*gn_w)
__global__ __launch_bounds__(256) void k_prep(const float* __restrict__ bw,
                                              const float* __restrict__ gw,
                                              const float* __restrict__ gb,
                                              const float* __restrict__ bb,
                                              const float* __restrict__ stats,
                                              float* __restrict__ w2,
                                              float* __restrict__ cc) {
  int o = blockIdx.x, n = threadIdx.x;
  float bwv = bw[o * 256 + n];
  float w2v = bwv * gw[n];
  w2[o * 256 + n] = w2v;
  float s1 = bwv * gb[n], s2 = w2v;
#pragma unroll
  for (int off = 32; off >= 1; off >>= 1) {
    s1 += __shfl_xor(s1, off, 64);
    s2 += __shfl_xor(s2, off, 64);
  }
  __shared__ float r1[4], r2[4];
  int wv = n >> 6, lane = n & 63;
  if (lane == 0) { r1[wv] = s1; r2[wv] = s2; }
  __syncthreads();
  if (n == 0) {
    float a1 = r1[0] + r1[1] + r1[2] + r1[3];
    float a2 = r2[0] + r2[1] + r2[2] + r2[3];
    for (int b = 0; b < 2; ++b)
      cc[b * 256 + o] = bb[o] + a1 - stats[4 + b * 2] * stats[5 + b * 2] * a2;
  }
}

// -------------------- rmsnorm over last dim (256) --------------------
__global__ __launch_bounds__(256) void k_rms(const float* __restrict__ x,
                                             const float* __restrict__ w,
                                             float* __restrict__ out) {
  int t = threadIdx.x;
  int row = blockIdx.x * 4 + (t >> 6);
  int lane = t & 63;
  if (row >= BLQ) return;
  float4 v = *(const float4*)&x[row * 256 + lane * 4];
  float ss = v.x * v.x + v.y * v.y + v.z * v.z + v.w * v.w;
#pragma unroll
  for (int off = 32; off >= 1; off >>= 1) ss += __shfl_xor(ss, off, 64);
  float r = 1.f / sqrtf(ss * (1.f / 256.f) + 1e-5f);
  float4 wv = *(const float4*)&w[lane * 4];
  float4 o;
  o.x = v.x * wv.x * r; o.y = v.y * wv.y * r;
  o.z = v.z * wv.z * r; o.w = v.w * wv.w * r;
  *(float4*)&out[row * 256 + lane * 4] = o;
}

// -------------------- generic 64x64 tiled fp32 GEMM, C = A * B^T (+mode epilogue) ----
// MODE 0: bottleneck  A=mw (col-gather + norm fold), B=w2, C=x (256)
// MODE 1: in-proj     A=xn (row-major K=256),  B=in_w[i] (2048x256), C=xz (2048)
// MODE 2: out-proj    A=g (dir-concat K=1024), B=out_w[i],           C+=  (256)
// MODE 3: masks       A=xn (row-major),        B=mask_w, epilogue relu*mw -> masked
// MODE 4: xproj       A=xc (per-dir, K=512),   B=xproj_w[i,dir] (48x512), C=xdbl (48)
template <int MODE>
__global__ __launch_bounds__(256) void gemm64(const float* __restrict__ A,
                                              const float* __restrict__ Bw,
                                              float* __restrict__ C,
                                              const float* __restrict__ aux1,
                                              const float* __restrict__ aux2,
                                              int M, int K,
                                              int aDS, int bDS, int cDS) {
  if (MODE == 4) {
    A += (size_t)blockIdx.z * aDS;
    Bw += (size_t)blockIdx.z * bDS;
    C += (size_t)blockIdx.z * cDS;
  }
  __shared__ float As[16][68];
  __shared__ float Bs[16][68];
  int t = threadIdx.x;
  int m0 = blockIdx.x * 64, n0 = blockIdx.y * 64;
  int tx = t & 15, ty = t >> 4;
  float acc[4][4] = {};
  for (int kk = 0; kk < K; kk += 16) {
    // ---- A tile ----
    if (MODE == 0) {
#pragma unroll
      for (int j = 0; j < 4; ++j) {
        int e = t + 256 * j;
        int m_ = e & 63, k_ = e >> 6;
        int m = m0 + m_;
        float v = 0.f;
        if (m < M) {
          int bb = m >= LQ;
          int l = m - bb * LQ;
          v = A[(size_t)((bb << 8) + kk + k_) * LQ + l];
        }
        As[k_][m_] = v;
      }
    } else {
      int m_ = t >> 2, k4 = (t & 3) * 4;
      int m = m0 + m_;
      float4 v = make_float4(0.f, 0.f, 0.f, 0.f);
      if (m < M) {
        if (MODE == 2) {
          int k = kk + k4;
          v = *(const float4*)&A[(size_t)(k >> 9) * aDS + (size_t)m * 512 + (k & 511)];
        } else {
          v = *(const float4*)&A[(size_t)m * K + kk + k4];
        }
      }
      As[k4 + 0][m_] = v.x; As[k4 + 1][m_] = v.y;
      As[k4 + 2][m_] = v.z; As[k4 + 3][m_] = v.w;
    }
    // ---- B tile ----
    {
      int n_ = t >> 2, k4 = (t & 3) * 4;
      int n = n0 + n_;
      float4 v = make_float4(0.f, 0.f, 0.f, 0.f);
      if (MODE != 4 || n_ < 48) {
        if (MODE == 2) {
          int k = kk + k4;
          v = *(const float4*)&Bw[(size_t)(k >> 9) * bDS + (size_t)n * 512 + (k & 511)];
        } else {
          v = *(const float4*)&Bw[(size_t)n * K + kk + k4];
        }
      }
      Bs[k4 + 0][n_] = v.x; Bs[k4 + 1][n_] = v.y;
      Bs[k4 + 2][n_] = v.z; Bs[k4 + 3][n_] = v.w;
    }
    __syncthreads();
#pragma unroll
    for (int k = 0; k < 16; ++k) {
      float4 av = *(const float4*)&As[k][ty * 4];
      float4 bv = *(const float4*)&Bs[k][tx * 4];
      acc[0][0] += av.x * bv.x; acc[0][1] += av.x * bv.y; acc[0][2] += av.x * bv.z; acc[0][3] += av.x * bv.w;
      acc[1][0] += av.y * bv.x; acc[1][1] += av.y * bv.y; acc[1][2] += av.y * bv.z; acc[1][3] += av.y * bv.w;
      acc[2][0] += av.z * bv.x; acc[2][1] += av.z * bv.y; acc[2][2] += av.z * bv.z; acc[2][3] += av.z * bv.w;
      acc[3][0] += av.w * bv.x; acc[3][1] += av.w * bv.y; acc[3][2] += av.w * bv.z; acc[3][3] += av.w * bv.w;
    }
    __syncthreads();
  }
  // ---- epilogue ----
#pragma unroll
  for (int i = 0; i < 4; ++i) {
    int m = m0 + ty * 4 + i;
    if (m < M) {
      int n = n0 + tx * 4;
      if (MODE == 0) {
        int bb = m >= LQ;
        float invb = aux1[5 + bb * 2];
        float4 cv = *(const float4*)&aux2[(bb << 8) + n];
        float4 o;
        o.x = acc[i][0] * invb + cv.x; o.y = acc[i][1] * invb + cv.y;
        o.z = acc[i][2] * invb + cv.z; o.w = acc[i][3] * invb + cv.w;
        *(float4*)&C[(size_t)m * 256 + n] = o;
      } else if (MODE == 1) {
        float4 o = {acc[i][0], acc[i][1], acc[i][2], acc[i][3]};
        *(float4*)&C[(size_t)m * 2048 + n] = o;
      } else if (MODE == 2) {
        float4 old = *(const float4*)&C[(size_t)m * 256 + n];
        old.x += acc[i][0]; old.y += acc[i][1];
        old.z += acc[i][2]; old.w += acc[i][3];
        *(float4*)&C[(size_t)m * 256 + n] = old;
      } else if (MODE == 3) {
        int bb = m >= LQ;
        int l = m - bb * LQ;
#pragma unroll
        for (int j = 0; j < 4; ++j) {
          int nc = n + j;
          float v = fmaxf(acc[i][j] + aux1[nc], 0.f);
          size_t idx = (size_t)((bb << 8) + nc) * LQ + l;
          C[idx] = v * aux2[idx];
        }
      } else {  // MODE 4
#pragma unroll
        for (int j = 0; j < 4; ++j) {
          int nc = n + j;
          if (nc < 48) C[(size_t)m * 48 + nc] = acc[i][j];
        }
      }
    }
  }
}

// -------------------- depthwise causal / anti-causal conv + silu --------------------
__global__ __launch_bounds__(256) void k_conv(const float* __restrict__ xz,
                                              const float* __restrict__ cwAll,
                                              const float* __restrict__ cbAll,
                                              float* __restrict__ xc, int blk) {
  int dir = blockIdx.y;
  int flat = blockIdx.x * 256 + threadIdx.x;   // exactly BLQ*512
  int d = flat & 511, bl = flat >> 9;
  int bb = bl >= LQ;
  int l = bl - bb * LQ;
  int w = blk * 2 + dir;
  const float* cw = cwAll + (size_t)(w * 512 + d) * 4;
  float acc = cbAll[w * 512 + d];
  int zoff = dir * 1024 + d;
#pragma unroll
  for (int j = 0; j < 4; ++j) {
    int ls = (dir == 0) ? (l - 3 + j) : (l + 3 - j);
    if (ls >= 0 && ls < LQ) acc += xz[(size_t)(bb * LQ + ls) * 2048 + zoff] * cw[j];
  }
  float sg = acc / (1.f + __expf(-acc));
  xc[(size_t)(dir * BLQ + bl) * 512 + d] = sg;
}

// -------------------- dt projection (K=16) + softplus --------------------
__global__ __launch_bounds__(256) void k_dt(const float* __restrict__ xdbl,
                                            const float* __restrict__ dtwAll,
                                            const float* __restrict__ dtbAll,
                                            float* __restrict__ dtg, int blk) {
  int dir = blockIdx.y;
  int flat = blockIdx.x * 256 + threadIdx.x;
  int d = flat & 511, bl = flat >> 9;
  int w = blk * 2 + dir;
  const float* xd = xdbl + (size_t)(dir * BLQ + bl) * 48;
  const float* Wp = dtwAll + (size_t)(w * 512 + d) * 16;
  float acc = dtbAll[w * 512 + d];
#pragma unroll
  for (int q = 0; q < 16; ++q) acc += xd[q] * Wp[q];
  float sp = fmaxf(acc, 0.f) + log1pf(expf(-fabsf(acc)));
  dtg[(size_t)(dir * BLQ + bl) * 512 + d] = sp;
}

// ==================== chunked selective scan ====================
// Decompose h_t = dA_t h_{t-1} + u_t over NCHK chunks of CHL steps:
//   pass1: per-chunk  prod = prod(dA),  loc = local scan from h=0
//   pass2: tiny sequential chain over chunks -> hstart per chunk
//   pass3: recompute local scan seeded with true hstart, emit gated y
// group id g = ((dir*2 + b)*512 + d)*NCHK + c ; lane s = state index

__global__ __launch_bounds__(256) void k_scan1(const float* __restrict__ dtg,
                                               const float* __restrict__ xc,
                                               const float* __restrict__ xdbl,
                                               const float* __restrict__ alog,
                                               float* __restrict__ prod,
                                               float* __restrict__ loc, int blk) {
  int t = threadIdx.x;
  int s = t & 15, grp = t >> 4;
  int g = blockIdx.x * 16 + grp;
  int c = g & (NCHK - 1);
  int d = (g >> 4) & 511;
  int b = (g >> 13) & 1;
  int dir = g >> 14;
  int w = blk * 2 + dir;
  float a2 = -__expf(alog[(size_t)(w * 512 + d) * 16 + s]) * 1.44269504f;
  const float* dtp = dtg + (size_t)dir * BLQ * 512;
  const float* xcp = xc + (size_t)dir * BLQ * 512;
  const float* xdp = xdbl + (size_t)dir * BLQ * 48;
  int b999 = b * LQ;
  int t0 = c * CHL;
  int len = min(CHL, LQ - t0);

  float h = 0.f, pr = 1.f;
  float cd[4], cx[4], cB[4], nd[4], nx[4], nB[4];
  auto LD = [&](int j, float& od, float& ox, float& oB) {
    if (j < len) {
      int l = dir ? (LQ - 1 - (t0 + j)) : (t0 + j);
      int bl = b999 + l;
      od = dtp[(size_t)bl * 512 + d];
      ox = xcp[(size_t)bl * 512 + d];
      oB = xdp[(size_t)bl * 48 + 16 + s];
    } else { od = 0.f; ox = 0.f; oB = 0.f; }   // dA=1, u=0 -> no-op steps
  };
#pragma unroll
  for (int j = 0; j < 4; ++j) LD(j, cd[j], cx[j], cB[j]);
  for (int j0 = 0; j0 < CHL; j0 += 4) {
#pragma unroll
    for (int j = 0; j < 4; ++j) LD(j0 + 4 + j, nd[j], nx[j], nB[j]);
#pragma unroll
    for (int j = 0; j < 4; ++j) {
      float dA = exp2f(cd[j] * a2);
      pr *= dA;
      h = dA * h + (cd[j] * cx[j]) * cB[j];
      cd[j] = nd[j]; cx[j] = nx[j]; cB[j] = nB[j];
    }
  }
  size_t idx = (size_t)g * 16 + s;
  prod[idx] = pr;
  loc[idx] = h;
}

__global__ __launch_bounds__(256) void k_scan2(const float* __restrict__ prod,
                                               const float* __restrict__ loc,
                                               float* __restrict__ hstart) {
  int t = threadIdx.x;
  int s = t & 15;
  int u = blockIdx.x * 16 + (t >> 4);     // u in [0, 2048): (dir,b,d)
  float pr[NCHK], lo[NCHK];
#pragma unroll
  for (int c = 0; c < NCHK; ++c) {
    size_t idx = ((size_t)(u * NCHK + c)) * 16 + s;
    pr[c] = prod[idx];
    lo[c] = loc[idx];
  }
  float h = 0.f;
#pragma unroll
  for (int c = 0; c < NCHK; ++c) {
    size_t idx = ((size_t)(u * NCHK + c)) * 16 + s;
    hstart[idx] = h;
    h = pr[c] * h + lo[c];
  }
}

__global__ __launch_bounds__(256) void k_scan3(const float* __restrict__ dtg,
                                               const float* __restrict__ xc,
                                               const float* __restrict__ xdbl,
                                               const float* __restrict__ xz,
                                               const float* __restrict__ alog,
                                               const float* __restrict__ dmat,
                                               const float* __restrict__ hstart,
                                               float* __restrict__ g_, int blk) {
  int t = threadIdx.x;
  int s = t & 15, grp = t >> 4;
  int g = blockIdx.x * 16 + grp;
  int c = g & (NCHK - 1);
  int d = (g >> 4) & 511;
  int b = (g >> 13) & 1;
  int dir = g >> 14;
  int w = blk * 2 + dir;
  float a2 = -__expf(alog[(size_t)(w * 512 + d) * 16 + s]) * 1.44269504f;
  float Dd = dmat[w * 512 + d];
  const float* dtp = dtg + (size_t)dir * BLQ * 512;
  const float* xcp = xc + (size_t)dir * BLQ * 512;
  const float* xdp = xdbl + (size_t)dir * BLQ * 48;
  const float* zp = xz + dir * 1024 + 512 + d;
  float* gp = g_ + (size_t)dir * BLQ * 512;
  int b999 = b * LQ;
  int t0 = c * CHL;
  int len = min(CHL, LQ - t0);

  float h = hstart[(size_t)g * 16 + s];
  float keepP = 0.f, keepXv = 0.f;
  int keepBl = 0;
  float cd[4], cx[4], cB[4], cC[4], nd[4], nx[4], nB[4], nC[4];
  auto LD = [&](int j, float& od, float& ox, float& oB, float& oC) {
    if (j < len) {
      int l = dir ? (LQ - 1 - (t0 + j)) : (t0 + j);
      int bl = b999 + l;
      od = dtp[(size_t)bl * 512 + d];
      ox = xcp[(size_t)bl * 512 + d];
      oB = xdp[(size_t)bl * 48 + 16 + s];
      oC = xdp[(size_t)bl * 48 + 32 + s];
    } else { od = 0.f; ox = 0.f; oB = 0.f; oC = 0.f; }
  };
#pragma unroll
  for (int j = 0; j < 4; ++j) LD(j, cd[j], cx[j], cB[j], cC[j]);
  for (int j0 = 0; j0 < CHL; j0 += 4) {
#pragma unroll
    for (int jj = 0; jj < 4; ++jj) LD(j0 + 4 + jj, nd[jj], nx[jj], nB[jj], nC[jj]);
#pragma unroll
    for (int jj = 0; jj < 4; ++jj) {
      int j = j0 + jj;
      if (j < len) {
        float dA = exp2f(cd[jj] * a2);
        h = dA * h + (cd[jj] * cx[jj]) * cB[jj];
        float p = h * cC[jj];
        p += __shfl_xor(p, 1, 16);
        p += __shfl_xor(p, 2, 16);
        p += __shfl_xor(p, 4, 16);
        p += __shfl_xor(p, 8, 16);
        int l = dir ? (LQ - 1 - (t0 + j)) : (t0 + j);
        int bl = b999 + l;
        if ((j & 15) == s) { keepP = p; keepXv = cx[jj]; keepBl = bl; }
        if ((j & 15) == 15 || j == len - 1) {
          int lim = j & 15;
          if (s <= lim) {
            float zv = zp[(size_t)keepBl * 2048];
            float sig = 1.f / (1.f + __expf(-zv));
            gp[(size_t)keepBl * 512 + d] = (keepP + keepXv * Dd) * (zv * sig);
          }
        }
      }
      cd[jj] = nd[jj]; cx[jj] = nx[jj]; cB[jj] = nB[jj]; cC[jj] = nC[jj];
    }
  }
}

// -------------------- transposed conv decoder --------------------
__global__ __launch_bounds__(256) void k_dec(const float* __restrict__ masked,
                                             const float* __restrict__ dw,
                                             float* __restrict__ out) {
  int idx = blockIdx.x * 256 + threadIdx.x;
  if (idx >= 16000) return;
  int b = idx >= 8000;
  int tt = idx - b * 8000;
  int j0 = tt & 7, l0 = tt >> 3;
  const float* mp = masked + (size_t)b * NCH * LQ;
  bool v0 = l0 <= LQ - 1;
  bool v1 = l0 >= 1;
  float acc = 0.f;
#pragma unroll 4
  for (int n = 0; n < 256; ++n) {
    const float* col = mp + (size_t)n * LQ;
    const float* wn = dw + n * 16;
    if (v0) acc += col[l0] * wn[j0];
    if (v1) acc += col[l0 - 1] * wn[j0 + 8];
  }
  out[idx] = acc;
}

// ==================== launch ====================
extern "C" void kernel_launch(void* const* d_in, const int* in_sizes, int n_in,
                              void* d_out, int out_size, void* d_ws, size_t ws_size,
                              hipStream_t stream) {
  const float* mixture = (const float*)d_in[0];
  const float* enc_w = (const float*)d_in[1];
  const float* dec_w = (const float*)d_in[2];
  const float* gn_w = (const float*)d_in[3];
  const float* gn_b = (const float*)d_in[4];
  const float* bot_w = (const float*)d_in[5];
  const float* bot_b = (const float*)d_in[6];
  const float* blk_norm_w = (const float*)d_in[7];
  const float* in_w = (const float*)d_in[8];
  const float* conv_w = (const float*)d_in[9];
  const float* conv_b = (const float*)d_in[10];
  const float* xproj_w = (const float*)d_in[11];
  const float* dt_w = (const float*)d_in[12];
  const float* dt_b = (const float*)d_in[13];
  const float* A_log = (const float*)d_in[14];
  const float* Dmat = (const float*)d_in[15];
  const float* out_w = (const float*)d_in[16];
  const float* normf_w = (const float*)d_in[17];
  const float* mask_w = (const float*)d_in[18];
  const float* mask_b = (const float*)d_in[19];
  float* outp = (float*)d_out;

  float* W = (float*)d_ws;
  size_t off = 0;
  auto alloc = [&](size_t n) {
    float* p = W + off;
    off += (n + 255) & ~(size_t)255;
    return p;
  };
  float* stats = alloc(8);          // [sum0,sq0,sum1,sq1, mu0,inv0, mu1,inv1]
  float* w2 = alloc(65536);
  float* cc = alloc(512);
  float* mw = alloc(511488);        // [b][n][l]
  float* x = alloc(511488);         // [bl][256]
  float* xn = alloc(511488);
  float* xzb = alloc(4091904);      // [bl][2048]
  float* xcb = alloc(2045952);      // [dir][bl][512]
  float* xdblb = alloc(191808);     // [dir][bl][48]
  float* dtgb = alloc(2045952);     // [dir][bl][512]
  float* gb = alloc(2045952);       // [dir][bl][512]  gated scan output
  float* maskedb = alloc(511488);   // [b][n][l]
  float* prodb = alloc(524288);     // [dir][b][d][chunk][s]
  float* locb = alloc(524288);
  float* hstartb = alloc(524288);

  hipMemsetAsync(stats, 0, 32, stream);
  k_enc<<<1998, 256, 0, stream>>>(mixture, enc_w, mw, stats);
  k_stats<<<1, 64, 0, stream>>>(stats);
  k_prep<<<256, 256, 0, stream>>>(bot_w, gn_w, gn_b, bot_b, stats, w2, cc);
  gemm64<0><<<dim3(32, 4, 1), 256, 0, stream>>>(mw, w2, x, stats, cc, BLQ, 256, 0, 0, 0);

  for (int i = 0; i < 8; ++i) {
    k_rms<<<500, 256, 0, stream>>>(x, blk_norm_w + i * 256, xn);
    gemm64<1><<<dim3(32, 32, 1), 256, 0, stream>>>(
        xn, in_w + (size_t)i * 2 * 1024 * 256, xzb, nullptr, nullptr, BLQ, 256, 0, 0, 0);
    k_conv<<<dim3(3996, 2, 1), 256, 0, stream>>>(xzb, conv_w, conv_b, xcb, i);
    gemm64<4><<<dim3(32, 1, 2), 256, 0, stream>>>(
        xcb, xproj_w + (size_t)i * 2 * 48 * 512, xdblb, nullptr, nullptr, BLQ, 512,
        BLQ * 512, 48 * 512, BLQ * 48);
    k_dt<<<dim3(3996, 2, 1), 256, 0, stream>>>(xdblb, dt_w, dt_b, dtgb, i);
    k_scan1<<<2048, 256, 0, stream>>>(dtgb, xcb, xdblb, A_log, prodb, locb, i);
    k_scan2<<<128, 256, 0, stream>>>(prodb, locb, hstartb);
    k_scan3<<<2048, 256, 0, stream>>>(dtgb, xcb, xdblb, xzb, A_log, Dmat, hstartb, gb, i);
    gemm64<2><<<dim3(32, 4, 1), 256, 0, stream>>>(
        gb, out_w + (size_t)i * 2 * 256 * 512, x, nullptr, nullptr, BLQ, 1024,
        BLQ * 512, 256 * 512, 0);
  }

  k_rms<<<500, 256, 0, stream>>>(x, normf_w, xn);
  gemm64<3><<<dim3(32, 4, 1), 256, 0, stream>>>(xn, mask_w, maskedb, mask_b, mw, BLQ, 256, 0, 0, 0);
  k_dec<<<63, 256, 0, stream>>>(maskedb, dec_w, outp);
}

// Round 6
// 1790.855 us; speedup vs baseline: 1.8900x; 1.4554x over previous
//
#include <hip/hip_runtime.h>
#include <cstdint>
#include <cmath>

// Shapes (fixed by the problem)
#define LQ   999      // conv output length (8000-16)/8+1
#define BLQ  1998     // BATCH * LQ
#define NCH  256      // encoder channels
#define NLTOT 255744  // NCH*LQ (per batch)
#define NCHK 16       // scan chunks per sequence
#define CHL  64       // chunk length (16*64=1024 >= 999)

// -------------------- encoder conv + relu + groupnorm partial sums --------------------
__global__ __launch_bounds__(256) void k_enc(const float* __restrict__ mix,
                                             const float* __restrict__ ew,
                                             float* __restrict__ mw,
                                             float* __restrict__ stats) {
  int t = threadIdx.x;
  int b = blockIdx.x >= LQ;
  int rem = (blockIdx.x - b * LQ) * 256 + t;
  int n = rem / LQ;
  int l = rem - n * LQ;
  const float* mp = mix + b * 8000 + l * 8;
  const float* wp = ew + n * 16;
  float acc = 0.f;
#pragma unroll
  for (int k = 0; k < 16; ++k) acc += mp[k] * wp[k];
  float v = fmaxf(acc, 0.f);
  mw[(b * NCH + n) * LQ + l] = v;
  float s1 = v, s2 = v * v;
#pragma unroll
  for (int off = 32; off >= 1; off >>= 1) {
    s1 += __shfl_xor(s1, off, 64);
    s2 += __shfl_xor(s2, off, 64);
  }
  __shared__ float r1[4], r2[4];
  int wv = t >> 6, lane = t & 63;
  if (lane == 0) { r1[wv] = s1; r2[wv] = s2; }
  __syncthreads();
  if (t == 0) {
    atomicAdd(&stats[b * 2 + 0], r1[0] + r1[1] + r1[2] + r1[3]);
    atomicAdd(&stats[b * 2 + 1], r2[0] + r2[1] + r2[2] + r2[3]);
  }
}

__global__ void k_stats(float* stats) {
  int t = threadIdx.x;
  if (t < 2) {
    float s = stats[t * 2 + 0], q = stats[t * 2 + 1];
    float mu = s / (float)NLTOT;
    float var = q / (float)NLTOT - mu * mu;
    stats[4 + t * 2 + 0] = mu;
    stats[4 + t * 2 + 1] = 1.f / sqrtf(var + 1e-5f);
  }
}

__global__ __launch_bounds__(256) void k_prep(const float* __restrict__ bw,
                                              const float* __restrict__ gw,
                                              const float* __restrict__ gb,
                                              const float* __restrict__ bb,
                                              const float* __restrict__ stats,
                                              float* __restrict__ w2,
                                              float* __restrict__ cc) {
  int o = blockIdx.x, n = threadIdx.x;
  float bwv = bw[o * 256 + n];
  float w2v = bwv * gw[n];
  w2[o * 256 + n] = w2v;
  float s1 = bwv * gb[n], s2 = w2v;
#pragma unroll
  for (int off = 32; off >= 1; off >>= 1) {
    s1 += __shfl_xor(s1, off, 64);
    s2 += __shfl_xor(s2, off, 64);
  }
  __shared__ float r1[4], r2[4];
  int wv = n >> 6, lane = n & 63;
  if (lane == 0) { r1[wv] = s1; r2[wv] = s2; }
  __syncthreads();
  if (n == 0) {
    float a1 = r1[0] + r1[1] + r1[2] + r1[3];
    float a2 = r2[0] + r2[1] + r2[2] + r2[3];
    for (int b = 0; b < 2; ++b)
      cc[b * 256 + o] = bb[o] + a1 - stats[4 + b * 2] * stats[5 + b * 2] * a2;
  }
}

// -------------------- rmsnorm over last dim (256) --------------------
__global__ __launch_bounds__(256) void k_rms(const float* __restrict__ x,
                                             const float* __restrict__ w,
                                             float* __restrict__ out) {
  int t = threadIdx.x;
  int row = blockIdx.x * 4 + (t >> 6);
  int lane = t & 63;
  if (row >= BLQ) return;
  float4 v = *(const float4*)&x[row * 256 + lane * 4];
  float ss = v.x * v.x + v.y * v.y + v.z * v.z + v.w * v.w;
#pragma unroll
  for (int off = 32; off >= 1; off >>= 1) ss += __shfl_xor(ss, off, 64);
  float r = 1.f / sqrtf(ss * (1.f / 256.f) + 1e-5f);
  float4 wv = *(const float4*)&w[lane * 4];
  float4 o;
  o.x = v.x * wv.x * r; o.y = v.y * wv.y * r;
  o.z = v.z * wv.z * r; o.w = v.w * wv.w * r;
  *(float4*)&out[row * 256 + lane * 4] = o;
}

// -------------------- generic 64x64 tiled fp32 GEMM, C = A * B^T (+mode epilogue) ----
// MODE 0: bottleneck  A=mw (col-gather + norm fold), B=w2, C=x (256)
// MODE 3: masks       A=xn (row-major), B=mask_w, epilogue relu*mw -> masked
// MODE 4: xproj       A=xc (per-dir, K=512), B=xproj_w[i,dir] (48x512), C=xdbl (48)
// MODE 5: out-proj splitK over dirs: A=g+z*aDS (K=512), B=out_w+z*bDS, atomicAdd C
template <int MODE>
__global__ __launch_bounds__(256) void gemm64(const float* __restrict__ A,
                                              const float* __restrict__ Bw,
                                              float* __restrict__ C,
                                              const float* __restrict__ aux1,
                                              const float* __restrict__ aux2,
                                              int M, int K,
                                              int aDS, int bDS, int cDS) {
  if (MODE == 4 || MODE == 5) {
    A += (size_t)blockIdx.z * aDS;
    Bw += (size_t)blockIdx.z * bDS;
    C += (size_t)blockIdx.z * cDS;
  }
  __shared__ float As[16][68];
  __shared__ float Bs[16][68];
  int t = threadIdx.x;
  int m0 = blockIdx.x * 64, n0 = blockIdx.y * 64;
  int tx = t & 15, ty = t >> 4;
  float acc[4][4] = {};
  for (int kk = 0; kk < K; kk += 16) {
    // ---- A tile ----
    if (MODE == 0) {
#pragma unroll
      for (int j = 0; j < 4; ++j) {
        int e = t + 256 * j;
        int m_ = e & 63, k_ = e >> 6;
        int m = m0 + m_;
        float v = 0.f;
        if (m < M) {
          int bb = m >= LQ;
          int l = m - bb * LQ;
          v = A[(size_t)((bb << 8) + kk + k_) * LQ + l];
        }
        As[k_][m_] = v;
      }
    } else {
      int m_ = t >> 2, k4 = (t & 3) * 4;
      int m = m0 + m_;
      float4 v = make_float4(0.f, 0.f, 0.f, 0.f);
      if (m < M) v = *(const float4*)&A[(size_t)m * K + kk + k4];
      As[k4 + 0][m_] = v.x; As[k4 + 1][m_] = v.y;
      As[k4 + 2][m_] = v.z; As[k4 + 3][m_] = v.w;
    }
    // ---- B tile ----
    {
      int n_ = t >> 2, k4 = (t & 3) * 4;
      int n = n0 + n_;
      float4 v = make_float4(0.f, 0.f, 0.f, 0.f);
      if (MODE != 4 || n_ < 48)
        v = *(const float4*)&Bw[(size_t)n * K + kk + k4];
      Bs[k4 + 0][n_] = v.x; Bs[k4 + 1][n_] = v.y;
      Bs[k4 + 2][n_] = v.z; Bs[k4 + 3][n_] = v.w;
    }
    __syncthreads();
#pragma unroll
    for (int k = 0; k < 16; ++k) {
      float4 av = *(const float4*)&As[k][ty * 4];
      float4 bv = *(const float4*)&Bs[k][tx * 4];
      acc[0][0] += av.x * bv.x; acc[0][1] += av.x * bv.y; acc[0][2] += av.x * bv.z; acc[0][3] += av.x * bv.w;
      acc[1][0] += av.y * bv.x; acc[1][1] += av.y * bv.y; acc[1][2] += av.y * bv.z; acc[1][3] += av.y * bv.w;
      acc[2][0] += av.z * bv.x; acc[2][1] += av.z * bv.y; acc[2][2] += av.z * bv.z; acc[2][3] += av.z * bv.w;
      acc[3][0] += av.w * bv.x; acc[3][1] += av.w * bv.y; acc[3][2] += av.w * bv.z; acc[3][3] += av.w * bv.w;
    }
    __syncthreads();
  }
  // ---- epilogue ----
#pragma unroll
  for (int i = 0; i < 4; ++i) {
    int m = m0 + ty * 4 + i;
    if (m < M) {
      int n = n0 + tx * 4;
      if (MODE == 0) {
        int bb = m >= LQ;
        float invb = aux1[5 + bb * 2];
        float4 cv = *(const float4*)&aux2[(bb << 8) + n];
        float4 o;
        o.x = acc[i][0] * invb + cv.x; o.y = acc[i][1] * invb + cv.y;
        o.z = acc[i][2] * invb + cv.z; o.w = acc[i][3] * invb + cv.w;
        *(float4*)&C[(size_t)m * 256 + n] = o;
      } else if (MODE == 3) {
        int bb = m >= LQ;
        int l = m - bb * LQ;
#pragma unroll
        for (int j = 0; j < 4; ++j) {
          int nc = n + j;
          float v = fmaxf(acc[i][j] + aux1[nc], 0.f);
          size_t idx = (size_t)((bb << 8) + nc) * LQ + l;
          C[idx] = v * aux2[idx];
        }
      } else if (MODE == 4) {
#pragma unroll
        for (int j = 0; j < 4; ++j) {
          int nc = n + j;
          if (nc < 48) C[(size_t)m * 48 + nc] = acc[i][j];
        }
      } else {  // MODE 5
#pragma unroll
        for (int j = 0; j < 4; ++j)
          atomicAdd(&C[(size_t)m * 256 + n + j], acc[i][j]);
      }
    }
  }
}

// -------------------- 128x128 tiled fp32 GEMM for in-proj ----------------------------
// C[BLQ][2048] = A[BLQ][256] * B[2048][256]^T
__global__ __launch_bounds__(256) void gemm128(const float* __restrict__ A,
                                               const float* __restrict__ Bw,
                                               float* __restrict__ C) {
  __shared__ float As[16][132];
  __shared__ float Bs[16][132];
  int t = threadIdx.x;
  int m0 = blockIdx.x * 128, n0 = blockIdx.y * 128;
  int tx = t & 15, ty = t >> 4;
  int rr = t >> 1, kh = (t & 1) * 8;
  float4 pa0, pa1, pb0, pb1;
  auto gload = [&](int kk) {
    int m = m0 + rr;
    if (m < BLQ) {
      pa0 = *(const float4*)&A[(size_t)m * 256 + kk + kh];
      pa1 = *(const float4*)&A[(size_t)m * 256 + kk + kh + 4];
    } else {
      pa0 = make_float4(0.f, 0.f, 0.f, 0.f);
      pa1 = make_float4(0.f, 0.f, 0.f, 0.f);
    }
    pb0 = *(const float4*)&Bw[(size_t)(n0 + rr) * 256 + kk + kh];
    pb1 = *(const float4*)&Bw[(size_t)(n0 + rr) * 256 + kk + kh + 4];
  };
  float acc[2][2][4][4] = {};
  gload(0);
  for (int kk = 0; kk < 256; kk += 16) {
    As[kh + 0][rr] = pa0.x; As[kh + 1][rr] = pa0.y; As[kh + 2][rr] = pa0.z; As[kh + 3][rr] = pa0.w;
    As[kh + 4][rr] = pa1.x; As[kh + 5][rr] = pa1.y; As[kh + 6][rr] = pa1.z; As[kh + 7][rr] = pa1.w;
    Bs[kh + 0][rr] = pb0.x; Bs[kh + 1][rr] = pb0.y; Bs[kh + 2][rr] = pb0.z; Bs[kh + 3][rr] = pb0.w;
    Bs[kh + 4][rr] = pb1.x; Bs[kh + 5][rr] = pb1.y; Bs[kh + 6][rr] = pb1.z; Bs[kh + 7][rr] = pb1.w;
    __syncthreads();
    if (kk + 16 < 256) gload(kk + 16);
#pragma unroll
    for (int k = 0; k < 16; ++k) {
      float4 a0 = *(const float4*)&As[k][ty * 4];
      float4 a1 = *(const float4*)&As[k][64 + ty * 4];
      float4 b0 = *(const float4*)&Bs[k][tx * 4];
      float4 b1 = *(const float4*)&Bs[k][64 + tx * 4];
      float av[2][4] = {{a0.x, a0.y, a0.z, a0.w}, {a1.x, a1.y, a1.z, a1.w}};
      float bv[2][4] = {{b0.x, b0.y, b0.z, b0.w}, {b1.x, b1.y, b1.z, b1.w}};
#pragma unroll
      for (int mh = 0; mh < 2; ++mh)
#pragma unroll
        for (int i = 0; i < 4; ++i)
#pragma unroll
          for (int nh = 0; nh < 2; ++nh)
#pragma unroll
            for (int j = 0; j < 4; ++j)
              acc[mh][nh][i][j] += av[mh][i] * bv[nh][j];
    }
    __syncthreads();
  }
#pragma unroll
  for (int mh = 0; mh < 2; ++mh)
#pragma unroll
    for (int i = 0; i < 4; ++i) {
      int m = m0 + mh * 64 + ty * 4 + i;
      if (m < BLQ) {
#pragma unroll
        for (int nh = 0; nh < 2; ++nh) {
          int n = n0 + nh * 64 + tx * 4;
          float4 o = {acc[mh][nh][i][0], acc[mh][nh][i][1], acc[mh][nh][i][2], acc[mh][nh][i][3]};
          *(float4*)&C[(size_t)m * 2048 + n] = o;
        }
      }
    }
}

// -------------------- depthwise causal / anti-causal conv + silu --------------------
__global__ __launch_bounds__(256) void k_conv(const float* __restrict__ xz,
                                              const float* __restrict__ cwAll,
                                              const float* __restrict__ cbAll,
                                              float* __restrict__ xc, int blk) {
  int dir = blockIdx.y;
  int flat = blockIdx.x * 256 + threadIdx.x;
  int d = flat & 511, bl = flat >> 9;
  int bb = bl >= LQ;
  int l = bl - bb * LQ;
  int w = blk * 2 + dir;
  const float* cw = cwAll + (size_t)(w * 512 + d) * 4;
  float acc = cbAll[w * 512 + d];
  int zoff = dir * 1024 + d;
#pragma unroll
  for (int j = 0; j < 4; ++j) {
    int ls = (dir == 0) ? (l - 3 + j) : (l + 3 - j);
    if (ls >= 0 && ls < LQ) acc += xz[(size_t)(bb * LQ + ls) * 2048 + zoff] * cw[j];
  }
  float sg = acc / (1.f + __expf(-acc));
  xc[(size_t)(dir * BLQ + bl) * 512 + d] = sg;
}

// -------------------- dt projection (K=16) + softplus --------------------
__global__ __launch_bounds__(256) void k_dt(const float* __restrict__ xdbl,
                                            const float* __restrict__ dtwAll,
                                            const float* __restrict__ dtbAll,
                                            float* __restrict__ dtg, int blk) {
  int dir = blockIdx.y;
  int flat = blockIdx.x * 256 + threadIdx.x;
  int d = flat & 511, bl = flat >> 9;
  int w = blk * 2 + dir;
  const float* xd = xdbl + (size_t)(dir * BLQ + bl) * 48;
  const float* Wp = dtwAll + (size_t)(w * 512 + d) * 16;
  float acc = dtbAll[w * 512 + d];
#pragma unroll
  for (int q = 0; q < 16; ++q) acc += xd[q] * Wp[q];
  float sp = fmaxf(acc, 0.f) + log1pf(expf(-fabsf(acc)));
  dtg[(size_t)(dir * BLQ + bl) * 512 + d] = sp;
}

// ==================== chunked selective scan, LDS-staged, two kernels ====================
// Block = 16 d-channels x 2 chunks.  grid 1024 = 2dir x 2b x 32dg x 8cpair.
// k_scanA: stage chunk to LDS (once), local scan -> prod/loc (global).
// k_scanC: per-thread 16-step chain over prod/loc -> hstart, then re-scan from LDS
//          seeded with hstart, emit gated y.  Kernel boundary = device-wide visibility
//          (replaces the cooperative grid.sync that failed in round 4).

__global__ __launch_bounds__(256) void k_scanA(const float* __restrict__ dtg,
                                               const float* __restrict__ xc,
                                               const float* __restrict__ xdbl,
                                               const float* __restrict__ alog,
                                               float* __restrict__ prod,
                                               float* __restrict__ loc, int blk) {
  __shared__ float s_dx[64 * 17 * 2];  // (j*17+dloc)*2 + {dt,x}
  __shared__ float s_bc[64 * 16 * 2];  // (j*16+s)*2  + {B,C}
  int t = threadIdx.x;
  int bid = blockIdx.x;
  int cpair = bid & 7;
  int wb = bid >> 3;            // (dir*2+b)*32+dg
  int dg = wb & 31;
  int b = (wb >> 5) & 1;
  int dir = wb >> 6;
  int dloc = t >> 4, s = t & 15;
  int d0 = dg * 16;
  int d = d0 + dloc;
  int w = blk * 2 + dir;
  int b999 = b * LQ;
  float a2 = -__expf(alog[(size_t)(w * 512 + d) * 16 + s]) * 1.44269504f;
  const float* dtp = dtg + (size_t)dir * BLQ * 512;
  const float* xcp = xc + (size_t)dir * BLQ * 512;
  const float* xdp = xdbl + (size_t)dir * BLQ * 48;
  size_t wbase = (size_t)wb * 4096;
  int c0 = cpair * 2;

  auto stage = [&](int cc) {
    int j16 = t >> 4, dl = t & 15;
#pragma unroll
    for (int it = 0; it < 4; ++it) {
      int j = it * 16 + j16;
      int tg = cc * 64 + j;
      float dtv = 0.f, xv = 0.f;
      if (tg < LQ) {
        int l = dir ? (LQ - 1 - tg) : tg;
        size_t bl = (size_t)(b999 + l);
        dtv = dtp[bl * 512 + d0 + dl];
        xv = xcp[bl * 512 + d0 + dl];
      }
      s_dx[(j * 17 + dl) * 2] = dtv;
      s_dx[(j * 17 + dl) * 2 + 1] = xv;
    }
    int j8 = t >> 5, idx = t & 31;
#pragma unroll
    for (int it = 0; it < 8; ++it) {
      int j = it * 8 + j8;
      int tg = cc * 64 + j;
      float v = 0.f;
      if (tg < LQ) {
        int l = dir ? (LQ - 1 - tg) : tg;
        v = xdp[(size_t)(b999 + l) * 48 + 16 + idx];
      }
      int ss = idx & 15, isC = idx >> 4;
      s_bc[(j * 16 + ss) * 2 + isC] = v;
    }
  };

#pragma unroll
  for (int ci = 0; ci < 2; ++ci) {
    int cc = c0 + ci;
    stage(cc);
    __syncthreads();
    float h = 0.f, pr = 1.f;
#pragma unroll 16
    for (int j = 0; j < 64; ++j) {
      float2 dx = *(float2*)&s_dx[(j * 17 + dloc) * 2];
      float Bv = s_bc[(j * 16 + s) * 2];
      float dA = exp2f(dx.x * a2);
      pr *= dA;
      h = dA * h + dx.x * dx.y * Bv;
    }
    prod[wbase + cc * 256 + t] = pr;
    loc[wbase + cc * 256 + t] = h;
    __syncthreads();
  }
}

__global__ __launch_bounds__(256) void k_scanC(const float* __restrict__ dtg,
                                               const float* __restrict__ xc,
                                               const float* __restrict__ xdbl,
                                               const float* __restrict__ xz,
                                               const float* __restrict__ alog,
                                               const float* __restrict__ dmat,
                                               const float* __restrict__ prod,
                                               const float* __restrict__ loc,
                                               float* __restrict__ g_, int blk) {
  __shared__ float s_dx[64 * 17 * 2];
  __shared__ float s_bc[64 * 16 * 2];
  int t = threadIdx.x;
  int bid = blockIdx.x;
  int cpair = bid & 7;
  int wb = bid >> 3;
  int dg = wb & 31;
  int b = (wb >> 5) & 1;
  int dir = wb >> 6;
  int dloc = t >> 4, s = t & 15;
  int d0 = dg * 16;
  int d = d0 + dloc;
  int w = blk * 2 + dir;
  int b999 = b * LQ;
  float a2 = -__expf(alog[(size_t)(w * 512 + d) * 16 + s]) * 1.44269504f;
  float Dd = dmat[w * 512 + d];
  const float* dtp = dtg + (size_t)dir * BLQ * 512;
  const float* xcp = xc + (size_t)dir * BLQ * 512;
  const float* xdp = xdbl + (size_t)dir * BLQ * 48;
  const float* zp = xz + dir * 1024 + 512 + d;
  float* gp = g_ + (size_t)dir * BLQ * 512;
  size_t wbase = (size_t)wb * 4096;
  int c0 = cpair * 2;

  auto stage = [&](int cc) {
    int j16 = t >> 4, dl = t & 15;
#pragma unroll
    for (int it = 0; it < 4; ++it) {
      int j = it * 16 + j16;
      int tg = cc * 64 + j;
      float dtv = 0.f, xv = 0.f;
      if (tg < LQ) {
        int l = dir ? (LQ - 1 - tg) : tg;
        size_t bl = (size_t)(b999 + l);
        dtv = dtp[bl * 512 + d0 + dl];
        xv = xcp[bl * 512 + d0 + dl];
      }
      s_dx[(j * 17 + dl) * 2] = dtv;
      s_dx[(j * 17 + dl) * 2 + 1] = xv;
    }
    int j8 = t >> 5, idx = t & 31;
#pragma unroll
    for (int it = 0; it < 8; ++it) {
      int j = it * 8 + j8;
      int tg = cc * 64 + j;
      float v = 0.f;
      if (tg < LQ) {
        int l = dir ? (LQ - 1 - tg) : tg;
        v = xdp[(size_t)(b999 + l) * 48 + 16 + idx];
      }
      int ss = idx & 15, isC = idx >> 4;
      s_bc[(j * 16 + ss) * 2 + isC] = v;
    }
  };

  // chain over 16 chunks (each thread: its own (dloc,s) lane state)
  float hs0 = 0.f, hs1 = 0.f;
  {
    float h = 0.f;
#pragma unroll
    for (int ccc = 0; ccc < NCHK; ++ccc) {
      if (ccc == c0) hs0 = h;
      if (ccc == c0 + 1) hs1 = h;
      float prv = prod[wbase + ccc * 256 + t];
      float lov = loc[wbase + ccc * 256 + t];
      h = prv * h + lov;
    }
  }

  auto zload = [&](int cc, int j0n) -> float {
    int tg = cc * 64 + j0n + s;
    if (j0n < 64 && tg < LQ) {
      int l = dir ? (LQ - 1 - tg) : tg;
      return zp[(size_t)(b999 + l) * 2048];
    }
    return 0.f;
  };

#pragma unroll
  for (int ci = 0; ci < 2; ++ci) {
    int cc = c0 + ci;
    stage(cc);
    __syncthreads();
    float h = ci ? hs1 : hs0;
    float keepP = 0.f;
    float zq = zload(cc, 0);
    for (int j0 = 0; j0 < 64; j0 += 16) {
#pragma unroll
      for (int jj = 0; jj < 16; ++jj) {
        int j = j0 + jj;
        float2 dx = *(float2*)&s_dx[(j * 17 + dloc) * 2];
        float2 bc = *(float2*)&s_bc[(j * 16 + s) * 2];
        float dA = exp2f(dx.x * a2);
        h = dA * h + dx.x * dx.y * bc.x;
        float p = h * bc.y;
        p += __shfl_xor(p, 1, 16);
        p += __shfl_xor(p, 2, 16);
        p += __shfl_xor(p, 4, 16);
        p += __shfl_xor(p, 8, 16);
        if (jj == s) keepP = p;
      }
      int tg = cc * 64 + j0 + s;
      float xv = s_dx[((j0 + s) * 17 + dloc) * 2 + 1];
      float zv = zq;
      zq = zload(cc, j0 + 16);
      float sig = 1.f / (1.f + __expf(-zv));
      float y = (keepP + xv * Dd) * (zv * sig);
      if (tg < LQ) {
        int l = dir ? (LQ - 1 - tg) : tg;
        gp[(size_t)(b999 + l) * 512 + d] = y;
      }
    }
    __syncthreads();
  }
}

// -------------------- transposed conv decoder --------------------
__global__ __launch_bounds__(256) void k_dec(const float* __restrict__ masked,
                                             const float* __restrict__ dw,
                                             float* __restrict__ out) {
  int idx = blockIdx.x * 256 + threadIdx.x;
  if (idx >= 16000) return;
  int b = idx >= 8000;
  int tt = idx - b * 8000;
  int j0 = tt & 7, l0 = tt >> 3;
  const float* mp = masked + (size_t)b * NCH * LQ;
  bool v0 = l0 <= LQ - 1;
  bool v1 = l0 >= 1;
  float acc = 0.f;
#pragma unroll 4
  for (int n = 0; n < 256; ++n) {
    const float* col = mp + (size_t)n * LQ;
    const float* wn = dw + n * 16;
    if (v0) acc += col[l0] * wn[j0];
    if (v1) acc += col[l0 - 1] * wn[j0 + 8];
  }
  out[idx] = acc;
}

// ==================== launch ====================
extern "C" void kernel_launch(void* const* d_in, const int* in_sizes, int n_in,
                              void* d_out, int out_size, void* d_ws, size_t ws_size,
                              hipStream_t stream) {
  const float* mixture = (const float*)d_in[0];
  const float* enc_w = (const float*)d_in[1];
  const float* dec_w = (const float*)d_in[2];
  const float* gn_w = (const float*)d_in[3];
  const float* gn_b = (const float*)d_in[4];
  const float* bot_w = (const float*)d_in[5];
  const float* bot_b = (const float*)d_in[6];
  const float* blk_norm_w = (const float*)d_in[7];
  const float* in_w = (const float*)d_in[8];
  const float* conv_w = (const float*)d_in[9];
  const float* conv_b = (const float*)d_in[10];
  const float* xproj_w = (const float*)d_in[11];
  const float* dt_w = (const float*)d_in[12];
  const float* dt_b = (const float*)d_in[13];
  const float* A_log = (const float*)d_in[14];
  const float* Dmat = (const float*)d_in[15];
  const float* out_w = (const float*)d_in[16];
  const float* normf_w = (const float*)d_in[17];
  const float* mask_w = (const float*)d_in[18];
  const float* mask_b = (const float*)d_in[19];
  float* outp = (float*)d_out;

  float* W = (float*)d_ws;
  size_t off = 0;
  auto alloc = [&](size_t n) {
    float* p = W + off;
    off += (n + 255) & ~(size_t)255;
    return p;
  };
  float* stats = alloc(8);
  float* w2 = alloc(65536);
  float* cc = alloc(512);
  float* mw = alloc(511488);        // [b][n][l]
  float* x = alloc(511488);         // [bl][256]
  float* xn = alloc(511488);
  float* xzb = alloc(4091904);      // [bl][2048]
  float* xcb = alloc(2045952);      // [dir][bl][512]
  float* xdblb = alloc(191808);     // [dir][bl][48]
  float* dtgb = alloc(2045952);     // [dir][bl][512]
  float* gb = alloc(2045952);       // [dir][bl][512]
  float* maskedb = alloc(511488);   // [b][n][l]
  float* prodb = alloc(524288);     // [wb][c][t]
  float* locb = alloc(524288);

  hipMemsetAsync(stats, 0, 32, stream);
  k_enc<<<1998, 256, 0, stream>>>(mixture, enc_w, mw, stats);
  k_stats<<<1, 64, 0, stream>>>(stats);
  k_prep<<<256, 256, 0, stream>>>(bot_w, gn_w, gn_b, bot_b, stats, w2, cc);
  gemm64<0><<<dim3(32, 4, 1), 256, 0, stream>>>(mw, w2, x, stats, cc, BLQ, 256, 0, 0, 0);

  for (int i = 0; i < 8; ++i) {
    k_rms<<<500, 256, 0, stream>>>(x, blk_norm_w + i * 256, xn);
    gemm128<<<dim3(16, 16), 256, 0, stream>>>(xn, in_w + (size_t)i * 2 * 1024 * 256, xzb);
    k_conv<<<dim3(3996, 2, 1), 256, 0, stream>>>(xzb, conv_w, conv_b, xcb, i);
    gemm64<4><<<dim3(32, 1, 2), 256, 0, stream>>>(
        xcb, xproj_w + (size_t)i * 2 * 48 * 512, xdblb, nullptr, nullptr, BLQ, 512,
        BLQ * 512, 48 * 512, BLQ * 48);
    k_dt<<<dim3(3996, 2, 1), 256, 0, stream>>>(xdblb, dt_w, dt_b, dtgb, i);
    k_scanA<<<1024, 256, 0, stream>>>(dtgb, xcb, xdblb, A_log, prodb, locb, i);
    k_scanC<<<1024, 256, 0, stream>>>(dtgb, xcb, xdblb, xzb, A_log, Dmat, prodb, locb, gb, i);
    gemm64<5><<<dim3(32, 4, 2), 256, 0, stream>>>(
        gb, out_w + (size_t)i * 2 * 256 * 512, x, nullptr, nullptr, BLQ, 512,
        BLQ * 512, 256 * 512, 0);
  }

  k_rms<<<500, 256, 0, stream>>>(x, normf_w, xn);
  gemm64<3><<<dim3(32, 4, 1), 256, 0, stream>>>(xn, mask_w, maskedb, mask_b, mw, BLQ, 256, 0, 0, 0);
  k_dec<<<63, 256, 0, stream>>>(maskedb, dec_w, outp);
}

// Round 7
// 1532.335 us; speedup vs baseline: 2.2089x; 1.1687x over previous
//
#include <hip/hip_runtime.h>
#include <cstdint>
#include <cmath>

// Shapes (fixed by the problem)
#define LQ   999      // conv output length (8000-16)/8+1
#define BLQ  1998     // BATCH * LQ
#define NCH  256      // encoder channels
#define NLTOT 255744  // NCH*LQ (per batch)
#define NCHK 16       // scan chunks per sequence
#define CHL  64       // chunk length (16*64=1024 >= 999)

typedef __attribute__((ext_vector_type(8))) short bf16x8;
typedef __attribute__((ext_vector_type(4))) float f32x4;

__device__ inline ushort f2bf(float f) {
  uint32_t u = __float_as_uint(f);
  u += 0x7fff + ((u >> 16) & 1);
  return (ushort)(u >> 16);
}

// -------------------- one-time weight quantize / transpose --------------------
// in_w (8*2048*256) -> bf16 ; out_w (8*2*256*512) -> bf16 ; dt_w transpose [w][d][q]->[w][q][d]
__global__ __launch_bounds__(256) void k_quant(const float* __restrict__ inw,
                                               const float* __restrict__ outw,
                                               const float* __restrict__ dtw,
                                               ushort* __restrict__ inwh,
                                               ushort* __restrict__ outwh,
                                               float* __restrict__ dtwt) {
  int i = blockIdx.x * 256 + threadIdx.x;
  if (i < 4194304) inwh[i] = f2bf(inw[i]);
  if (i < 2097152) outwh[i] = f2bf(outw[i]);
  if (i < 131072) {
    int w = i >> 13, d = (i >> 4) & 511, q = i & 15;
    dtwt[(w << 13) + q * 512 + d] = dtw[i];
  }
}

// -------------------- encoder conv + relu + groupnorm partial sums --------------------
__global__ __launch_bounds__(256) void k_enc(const float* __restrict__ mix,
                                             const float* __restrict__ ew,
                                             float* __restrict__ mw,
                                             float* __restrict__ stats) {
  int t = threadIdx.x;
  int b = blockIdx.x >= LQ;
  int rem = (blockIdx.x - b * LQ) * 256 + t;
  int n = rem / LQ;
  int l = rem - n * LQ;
  const float* mp = mix + b * 8000 + l * 8;
  const float* wp = ew + n * 16;
  float acc = 0.f;
#pragma unroll
  for (int k = 0; k < 16; ++k) acc += mp[k] * wp[k];
  float v = fmaxf(acc, 0.f);
  mw[(b * NCH + n) * LQ + l] = v;
  float s1 = v, s2 = v * v;
#pragma unroll
  for (int off = 32; off >= 1; off >>= 1) {
    s1 += __shfl_xor(s1, off, 64);
    s2 += __shfl_xor(s2, off, 64);
  }
  __shared__ float r1[4], r2[4];
  int wv = t >> 6, lane = t & 63;
  if (lane == 0) { r1[wv] = s1; r2[wv] = s2; }
  __syncthreads();
  if (t == 0) {
    atomicAdd(&stats[b * 2 + 0], r1[0] + r1[1] + r1[2] + r1[3]);
    atomicAdd(&stats[b * 2 + 1], r2[0] + r2[1] + r2[2] + r2[3]);
  }
}

__global__ void k_stats(float* stats) {
  int t = threadIdx.x;
  if (t < 2) {
    float s = stats[t * 2 + 0], q = stats[t * 2 + 1];
    float mu = s / (float)NLTOT;
    float var = q / (float)NLTOT - mu * mu;
    stats[4 + t * 2 + 0] = mu;
    stats[4 + t * 2 + 1] = 1.f / sqrtf(var + 1e-5f);
  }
}

__global__ __launch_bounds__(256) void k_prep(const float* __restrict__ bw,
                                              const float* __restrict__ gw,
                                              const float* __restrict__ gb,
                                              const float* __restrict__ bb,
                                              const float* __restrict__ stats,
                                              float* __restrict__ w2,
                                              float* __restrict__ cc) {
  int o = blockIdx.x, n = threadIdx.x;
  float bwv = bw[o * 256 + n];
  float w2v = bwv * gw[n];
  w2[o * 256 + n] = w2v;
  float s1 = bwv * gb[n], s2 = w2v;
#pragma unroll
  for (int off = 32; off >= 1; off >>= 1) {
    s1 += __shfl_xor(s1, off, 64);
    s2 += __shfl_xor(s2, off, 64);
  }
  __shared__ float r1[4], r2[4];
  int wv = n >> 6, lane = n & 63;
  if (lane == 0) { r1[wv] = s1; r2[wv] = s2; }
  __syncthreads();
  if (n == 0) {
    float a1 = r1[0] + r1[1] + r1[2] + r1[3];
    float a2 = r2[0] + r2[1] + r2[2] + r2[3];
    for (int b = 0; b < 2; ++b)
      cc[b * 256 + o] = bb[o] + a1 - stats[4 + b * 2] * stats[5 + b * 2] * a2;
  }
}

// -------------------- rmsnorm over last dim (256); BF=true writes bf16 --------------------
template <bool BF>
__global__ __launch_bounds__(256) void k_rms(const float* __restrict__ x,
                                             const float* __restrict__ w,
                                             float* __restrict__ out,
                                             ushort* __restrict__ outh) {
  int t = threadIdx.x;
  int row = blockIdx.x * 4 + (t >> 6);
  int lane = t & 63;
  if (row >= BLQ) return;
  float4 v = *(const float4*)&x[row * 256 + lane * 4];
  float ss = v.x * v.x + v.y * v.y + v.z * v.z + v.w * v.w;
#pragma unroll
  for (int off = 32; off >= 1; off >>= 1) ss += __shfl_xor(ss, off, 64);
  float r = 1.f / sqrtf(ss * (1.f / 256.f) + 1e-5f);
  float4 wv = *(const float4*)&w[lane * 4];
  float4 o;
  o.x = v.x * wv.x * r; o.y = v.y * wv.y * r;
  o.z = v.z * wv.z * r; o.w = v.w * wv.w * r;
  if (BF) {
    ushort4 oh = {f2bf(o.x), f2bf(o.y), f2bf(o.z), f2bf(o.w)};
    *(ushort4*)&outh[row * 256 + lane * 4] = oh;
  } else {
    *(float4*)&out[row * 256 + lane * 4] = o;
  }
}

// -------------------- generic 64x64 tiled fp32 GEMM, C = A * B^T (+mode epilogue) ----
// MODE 0: bottleneck  A=mw (col-gather + norm fold), B=w2, C=x (256)
// MODE 3: masks       A=xn (row-major), B=mask_w, epilogue relu*mw -> masked_t[bl][256]
// MODE 4: xproj       A=xc (per-dir, K=512), B=xproj_w[i,dir] (48x512), C=xdbl (48)
template <int MODE>
__global__ __launch_bounds__(256) void gemm64(const float* __restrict__ A,
                                              const float* __restrict__ Bw,
                                              float* __restrict__ C,
                                              const float* __restrict__ aux1,
                                              const float* __restrict__ aux2,
                                              int M, int K,
                                              int aDS, int bDS, int cDS) {
  if (MODE == 4) {
    A += (size_t)blockIdx.z * aDS;
    Bw += (size_t)blockIdx.z * bDS;
    C += (size_t)blockIdx.z * cDS;
  }
  __shared__ float As[16][68];
  __shared__ float Bs[16][68];
  int t = threadIdx.x;
  int m0 = blockIdx.x * 64, n0 = blockIdx.y * 64;
  int tx = t & 15, ty = t >> 4;
  float acc[4][4] = {};
  for (int kk = 0; kk < K; kk += 16) {
    // ---- A tile ----
    if (MODE == 0) {
#pragma unroll
      for (int j = 0; j < 4; ++j) {
        int e = t + 256 * j;
        int m_ = e & 63, k_ = e >> 6;
        int m = m0 + m_;
        float v = 0.f;
        if (m < M) {
          int bb = m >= LQ;
          int l = m - bb * LQ;
          v = A[(size_t)((bb << 8) + kk + k_) * LQ + l];
        }
        As[k_][m_] = v;
      }
    } else {
      int m_ = t >> 2, k4 = (t & 3) * 4;
      int m = m0 + m_;
      float4 v = make_float4(0.f, 0.f, 0.f, 0.f);
      if (m < M) v = *(const float4*)&A[(size_t)m * K + kk + k4];
      As[k4 + 0][m_] = v.x; As[k4 + 1][m_] = v.y;
      As[k4 + 2][m_] = v.z; As[k4 + 3][m_] = v.w;
    }
    // ---- B tile ----
    {
      int n_ = t >> 2, k4 = (t & 3) * 4;
      int n = n0 + n_;
      float4 v = make_float4(0.f, 0.f, 0.f, 0.f);
      if (MODE != 4 || n_ < 48)
        v = *(const float4*)&Bw[(size_t)n * K + kk + k4];
      Bs[k4 + 0][n_] = v.x; Bs[k4 + 1][n_] = v.y;
      Bs[k4 + 2][n_] = v.z; Bs[k4 + 3][n_] = v.w;
    }
    __syncthreads();
#pragma unroll
    for (int k = 0; k < 16; ++k) {
      float4 av = *(const float4*)&As[k][ty * 4];
      float4 bv = *(const float4*)&Bs[k][tx * 4];
      acc[0][0] += av.x * bv.x; acc[0][1] += av.x * bv.y; acc[0][2] += av.x * bv.z; acc[0][3] += av.x * bv.w;
      acc[1][0] += av.y * bv.x; acc[1][1] += av.y * bv.y; acc[1][2] += av.y * bv.z; acc[1][3] += av.y * bv.w;
      acc[2][0] += av.z * bv.x; acc[2][1] += av.z * bv.y; acc[2][2] += av.z * bv.z; acc[2][3] += av.z * bv.w;
      acc[3][0] += av.w * bv.x; acc[3][1] += av.w * bv.y; acc[3][2] += av.w * bv.z; acc[3][3] += av.w * bv.w;
    }
    __syncthreads();
  }
  // ---- epilogue ----
#pragma unroll
  for (int i = 0; i < 4; ++i) {
    int m = m0 + ty * 4 + i;
    if (m < M) {
      int n = n0 + tx * 4;
      if (MODE == 0) {
        int bb = m >= LQ;
        float invb = aux1[5 + bb * 2];
        float4 cv = *(const float4*)&aux2[(bb << 8) + n];
        float4 o;
        o.x = acc[i][0] * invb + cv.x; o.y = acc[i][1] * invb + cv.y;
        o.z = acc[i][2] * invb + cv.z; o.w = acc[i][3] * invb + cv.w;
        *(float4*)&C[(size_t)m * 256 + n] = o;
      } else if (MODE == 3) {
        int bb = m >= LQ;
        int l = m - bb * LQ;
        float4 o;
#pragma unroll
        for (int j = 0; j < 4; ++j) {
          int nc = n + j;
          float v = fmaxf(acc[i][j] + aux1[nc], 0.f);
          float mwv = aux2[(size_t)((bb << 8) + nc) * LQ + l];
          ((float*)&o)[j] = v * mwv;
        }
        *(float4*)&C[(size_t)m * 256 + n] = o;   // masked_t[bl][n] coalesced
      } else {  // MODE 4
#pragma unroll
        for (int j = 0; j < 4; ++j) {
          int nc = n + j;
          if (nc < 48) C[(size_t)m * 48 + nc] = acc[i][j];
        }
      }
    }
  }
}

// -------------------- MFMA bf16 GEMM #1: in-proj --------------------
// C[BLQ][2048] = A(xnh [BLQ][256]) * B(inwh[i] [2048][256])^T ; fp32 out
__global__ __launch_bounds__(256) void k_mm1(const ushort* __restrict__ Ah,
                                             const ushort* __restrict__ Bh,
                                             float* __restrict__ C) {
  int lane = threadIdx.x & 63, wid = threadIdx.x >> 6;
  int mbase = blockIdx.x * 128 + (wid >> 1) * 64;
  int nbase = blockIdx.y * 128 + (wid & 1) * 64;
  int lm = lane & 15, lk = (lane >> 4) * 8;
  f32x4 acc[4][4] = {};
  for (int ks = 0; ks < 256; ks += 32) {
    bf16x8 a[4], b[4];
#pragma unroll
    for (int mi = 0; mi < 4; ++mi) {
      int row = mbase + mi * 16 + lm;
      row = row < BLQ ? row : BLQ - 1;
      a[mi] = *(const bf16x8*)&Ah[(size_t)row * 256 + ks + lk];
    }
#pragma unroll
    for (int ni = 0; ni < 4; ++ni) {
      int nr = nbase + ni * 16 + lm;
      b[ni] = *(const bf16x8*)&Bh[(size_t)nr * 256 + ks + lk];
    }
#pragma unroll
    for (int mi = 0; mi < 4; ++mi)
#pragma unroll
      for (int ni = 0; ni < 4; ++ni)
        acc[mi][ni] = __builtin_amdgcn_mfma_f32_16x16x32_bf16(a[mi], b[ni], acc[mi][ni], 0, 0, 0);
  }
  int rbase = (lane >> 4) * 4;
#pragma unroll
  for (int mi = 0; mi < 4; ++mi)
#pragma unroll
    for (int r = 0; r < 4; ++r) {
      int m = mbase + mi * 16 + rbase + r;
      if (m < BLQ) {
#pragma unroll
        for (int ni = 0; ni < 4; ++ni)
          C[(size_t)m * 2048 + nbase + ni * 16 + lm] = acc[mi][ni][r];
      }
    }
}

// -------------------- MFMA bf16 GEMM #2: out-proj (accumulate into x) --------------------
// x[BLQ][256] += A(gh [2][BLQ][512], K=1024 dir-concat) * B(outwh[i] [2][256][512])^T
__global__ __launch_bounds__(256) void k_mm2(const ushort* __restrict__ Ah,
                                             const ushort* __restrict__ Bh,
                                             float* __restrict__ C) {
  int lane = threadIdx.x & 63, wid = threadIdx.x >> 6;
  int mbase = blockIdx.x * 128 + (wid >> 1) * 64;
  int nbase = blockIdx.y * 128 + (wid & 1) * 64;
  int lm = lane & 15, lk = (lane >> 4) * 8;
  f32x4 acc[4][4] = {};
  for (int ks = 0; ks < 1024; ks += 32) {
    int dir = ks >> 9;
    int di = (ks & 511) + lk;
    const ushort* Ab = Ah + (size_t)dir * BLQ * 512 + di;
    const ushort* Bb = Bh + (size_t)dir * 131072 + di;
    bf16x8 a[4], b[4];
#pragma unroll
    for (int mi = 0; mi < 4; ++mi) {
      int row = mbase + mi * 16 + lm;
      row = row < BLQ ? row : BLQ - 1;
      a[mi] = *(const bf16x8*)&Ab[(size_t)row * 512];
    }
#pragma unroll
    for (int ni = 0; ni < 4; ++ni) {
      int nr = nbase + ni * 16 + lm;
      b[ni] = *(const bf16x8*)&Bb[(size_t)nr * 512];
    }
#pragma unroll
    for (int mi = 0; mi < 4; ++mi)
#pragma unroll
      for (int ni = 0; ni < 4; ++ni)
        acc[mi][ni] = __builtin_amdgcn_mfma_f32_16x16x32_bf16(a[mi], b[ni], acc[mi][ni], 0, 0, 0);
  }
  int rbase = (lane >> 4) * 4;
#pragma unroll
  for (int mi = 0; mi < 4; ++mi)
#pragma unroll
    for (int r = 0; r < 4; ++r) {
      int m = mbase + mi * 16 + rbase + r;
      if (m < BLQ) {
#pragma unroll
        for (int ni = 0; ni < 4; ++ni) {
          size_t idx = (size_t)m * 256 + nbase + ni * 16 + lm;
          C[idx] += acc[mi][ni][r];
        }
      }
    }
}

// -------------------- depthwise causal / anti-causal conv + silu --------------------
__global__ __launch_bounds__(256) void k_conv(const float* __restrict__ xz,
                                              const float* __restrict__ cwAll,
                                              const float* __restrict__ cbAll,
                                              float* __restrict__ xc, int blk) {
  int dir = blockIdx.y;
  int flat = blockIdx.x * 256 + threadIdx.x;
  int d = flat & 511, bl = flat >> 9;
  int bb = bl >= LQ;
  int l = bl - bb * LQ;
  int w = blk * 2 + dir;
  const float* cw = cwAll + (size_t)(w * 512 + d) * 4;
  float acc = cbAll[w * 512 + d];
  int zoff = dir * 1024 + d;
#pragma unroll
  for (int j = 0; j < 4; ++j) {
    int ls = (dir == 0) ? (l - 3 + j) : (l + 3 - j);
    if (ls >= 0 && ls < LQ) acc += xz[(size_t)(bb * LQ + ls) * 2048 + zoff] * cw[j];
  }
  float sg = acc / (1.f + __expf(-acc));
  xc[(size_t)(dir * BLQ + bl) * 512 + d] = sg;
}

// -------------------- dt projection (K=16, transposed weights) + softplus --------------------
__global__ __launch_bounds__(256) void k_dt(const float* __restrict__ xdbl,
                                            const float* __restrict__ dtwt,
                                            const float* __restrict__ dtbAll,
                                            float* __restrict__ dtg, int blk) {
  int dir = blockIdx.y;
  int flat = blockIdx.x * 256 + threadIdx.x;
  int d = flat & 511, bl = flat >> 9;
  int w = blk * 2 + dir;
  const float* xd = xdbl + (size_t)(dir * BLQ + bl) * 48;
  const float* Wp = dtwt + (w << 13);
  float acc = dtbAll[w * 512 + d];
#pragma unroll
  for (int q = 0; q < 16; ++q) acc += xd[q] * Wp[q * 512 + d];
  float sp = fmaxf(acc, 0.f) + log1pf(expf(-fabsf(acc)));
  dtg[(size_t)(dir * BLQ + bl) * 512 + d] = sp;
}

// ==================== chunked selective scan, LDS-staged, two kernels ====================
__global__ __launch_bounds__(256) void k_scanA(const float* __restrict__ dtg,
                                               const float* __restrict__ xc,
                                               const float* __restrict__ xdbl,
                                               const float* __restrict__ alog,
                                               float* __restrict__ prod,
                                               float* __restrict__ loc, int blk) {
  __shared__ float s_dx[64 * 17 * 2];
  __shared__ float s_bc[64 * 16 * 2];
  int t = threadIdx.x;
  int bid = blockIdx.x;
  int cpair = bid & 7;
  int wb = bid >> 3;
  int dg = wb & 31;
  int b = (wb >> 5) & 1;
  int dir = wb >> 6;
  int dloc = t >> 4, s = t & 15;
  int d0 = dg * 16;
  int d = d0 + dloc;
  int w = blk * 2 + dir;
  int b999 = b * LQ;
  float a2 = -__expf(alog[(size_t)(w * 512 + d) * 16 + s]) * 1.44269504f;
  const float* dtp = dtg + (size_t)dir * BLQ * 512;
  const float* xcp = xc + (size_t)dir * BLQ * 512;
  const float* xdp = xdbl + (size_t)dir * BLQ * 48;
  size_t wbase = (size_t)wb * 4096;
  int c0 = cpair * 2;

  auto stage = [&](int cc) {
    int j16 = t >> 4, dl = t & 15;
#pragma unroll
    for (int it = 0; it < 4; ++it) {
      int j = it * 16 + j16;
      int tg = cc * 64 + j;
      float dtv = 0.f, xv = 0.f;
      if (tg < LQ) {
        int l = dir ? (LQ - 1 - tg) : tg;
        size_t bl = (size_t)(b999 + l);
        dtv = dtp[bl * 512 + d0 + dl];
        xv = xcp[bl * 512 + d0 + dl];
      }
      s_dx[(j * 17 + dl) * 2] = dtv;
      s_dx[(j * 17 + dl) * 2 + 1] = xv;
    }
    int j8 = t >> 5, idx = t & 31;
#pragma unroll
    for (int it = 0; it < 8; ++it) {
      int j = it * 8 + j8;
      int tg = cc * 64 + j;
      float v = 0.f;
      if (tg < LQ) {
        int l = dir ? (LQ - 1 - tg) : tg;
        v = xdp[(size_t)(b999 + l) * 48 + 16 + idx];
      }
      int ss = idx & 15, isC = idx >> 4;
      s_bc[(j * 16 + ss) * 2 + isC] = v;
    }
  };

#pragma unroll
  for (int ci = 0; ci < 2; ++ci) {
    int cc = c0 + ci;
    stage(cc);
    __syncthreads();
    float h = 0.f, pr = 1.f;
#pragma unroll 16
    for (int j = 0; j < 64; ++j) {
      float2 dx = *(float2*)&s_dx[(j * 17 + dloc) * 2];
      float Bv = s_bc[(j * 16 + s) * 2];
      float dA = exp2f(dx.x * a2);
      pr *= dA;
      h = dA * h + dx.x * dx.y * Bv;
    }
    prod[wbase + cc * 256 + t] = pr;
    loc[wbase + cc * 256 + t] = h;
    __syncthreads();
  }
}

__global__ __launch_bounds__(256) void k_scanC(const float* __restrict__ dtg,
                                               const float* __restrict__ xc,
                                               const float* __restrict__ xdbl,
                                               const float* __restrict__ xz,
                                               const float* __restrict__ alog,
                                               const float* __restrict__ dmat,
                                               const float* __restrict__ prod,
                                               const float* __restrict__ loc,
                                               ushort* __restrict__ gh, int blk) {
  __shared__ float s_dx[64 * 17 * 2];
  __shared__ float s_bc[64 * 16 * 2];
  int t = threadIdx.x;
  int bid = blockIdx.x;
  int cpair = bid & 7;
  int wb = bid >> 3;
  int dg = wb & 31;
  int b = (wb >> 5) & 1;
  int dir = wb >> 6;
  int dloc = t >> 4, s = t & 15;
  int d0 = dg * 16;
  int d = d0 + dloc;
  int w = blk * 2 + dir;
  int b999 = b * LQ;
  float a2 = -__expf(alog[(size_t)(w * 512 + d) * 16 + s]) * 1.44269504f;
  float Dd = dmat[w * 512 + d];
  const float* dtp = dtg + (size_t)dir * BLQ * 512;
  const float* xcp = xc + (size_t)dir * BLQ * 512;
  const float* xdp = xdbl + (size_t)dir * BLQ * 48;
  const float* zp = xz + dir * 1024 + 512 + d;
  ushort* gp = gh + (size_t)dir * BLQ * 512;
  size_t wbase = (size_t)wb * 4096;
  int c0 = cpair * 2;

  auto stage = [&](int cc) {
    int j16 = t >> 4, dl = t & 15;
#pragma unroll
    for (int it = 0; it < 4; ++it) {
      int j = it * 16 + j16;
      int tg = cc * 64 + j;
      float dtv = 0.f, xv = 0.f;
      if (tg < LQ) {
        int l = dir ? (LQ - 1 - tg) : tg;
        size_t bl = (size_t)(b999 + l);
        dtv = dtp[bl * 512 + d0 + dl];
        xv = xcp[bl * 512 + d0 + dl];
      }
      s_dx[(j * 17 + dl) * 2] = dtv;
      s_dx[(j * 17 + dl) * 2 + 1] = xv;
    }
    int j8 = t >> 5, idx = t & 31;
#pragma unroll
    for (int it = 0; it < 8; ++it) {
      int j = it * 8 + j8;
      int tg = cc * 64 + j;
      float v = 0.f;
      if (tg < LQ) {
        int l = dir ? (LQ - 1 - tg) : tg;
        v = xdp[(size_t)(b999 + l) * 48 + 16 + idx];
      }
      int ss = idx & 15, isC = idx >> 4;
      s_bc[(j * 16 + ss) * 2 + isC] = v;
    }
  };

  // chain over 16 chunks
  float hs0 = 0.f, hs1 = 0.f;
  {
    float h = 0.f;
#pragma unroll
    for (int ccc = 0; ccc < NCHK; ++ccc) {
      if (ccc == c0) hs0 = h;
      if (ccc == c0 + 1) hs1 = h;
      float prv = prod[wbase + ccc * 256 + t];
      float lov = loc[wbase + ccc * 256 + t];
      h = prv * h + lov;
    }
  }

  auto zload = [&](int cc, int j0n) -> float {
    int tg = cc * 64 + j0n + s;
    if (j0n < 64 && tg < LQ) {
      int l = dir ? (LQ - 1 - tg) : tg;
      return zp[(size_t)(b999 + l) * 2048];
    }
    return 0.f;
  };

#pragma unroll
  for (int ci = 0; ci < 2; ++ci) {
    int cc = c0 + ci;
    stage(cc);
    __syncthreads();
    float h = ci ? hs1 : hs0;
    float keepP = 0.f;
    float zq = zload(cc, 0);
    for (int j0 = 0; j0 < 64; j0 += 16) {
#pragma unroll
      for (int jj = 0; jj < 16; ++jj) {
        int j = j0 + jj;
        float2 dx = *(float2*)&s_dx[(j * 17 + dloc) * 2];
        float2 bc = *(float2*)&s_bc[(j * 16 + s) * 2];
        float dA = exp2f(dx.x * a2);
        h = dA * h + dx.x * dx.y * bc.x;
        float p = h * bc.y;
        p += __shfl_xor(p, 1, 16);
        p += __shfl_xor(p, 2, 16);
        p += __shfl_xor(p, 4, 16);
        p += __shfl_xor(p, 8, 16);
        if (jj == s) keepP = p;
      }
      int tg = cc * 64 + j0 + s;
      float xv = s_dx[((j0 + s) * 17 + dloc) * 2 + 1];
      float zv = zq;
      zq = zload(cc, j0 + 16);
      float sig = 1.f / (1.f + __expf(-zv));
      float y = (keepP + xv * Dd) * (zv * sig);
      if (tg < LQ) {
        int l = dir ? (LQ - 1 - tg) : tg;
        gp[(size_t)(b999 + l) * 512 + d] = f2bf(y);
      }
    }
    __syncthreads();
  }
}

// -------------------- decoder as GEMM: Z[b][l][16] = masked_t[b*LQ+l][:] @ dec_w --------------------
__global__ __launch_bounds__(256) void k_zg(const float* __restrict__ Mt,
                                            const float* __restrict__ dw,
                                            float* __restrict__ Z) {
  __shared__ float sm[16][260];
  __shared__ float sw[256][16];
  int t = threadIdx.x;
  int b = blockIdx.x >= 63;
  int r0 = (blockIdx.x - b * 63) * 16;
#pragma unroll
  for (int it = 0; it < 16; ++it) {
    int e = it * 256 + t;
    int r = e >> 8, c = e & 255;
    int l = r0 + r;
    sm[r][c] = (l < LQ) ? Mt[(size_t)(b * LQ + l) * 256 + c] : 0.f;
    sw[e >> 4][e & 15] = dw[e];
  }
  __syncthreads();
  int lrow = t >> 4, j = t & 15;
  float acc = 0.f;
#pragma unroll 8
  for (int n = 0; n < 256; ++n) acc += sm[lrow][n] * sw[n][j];
  int l = r0 + lrow;
  Z[(size_t)(b * 1008 + l) * 16 + j] = acc;
}

__global__ __launch_bounds__(256) void k_comb(const float* __restrict__ Z,
                                              float* __restrict__ out) {
  int idx = blockIdx.x * 256 + threadIdx.x;
  if (idx >= 16000) return;
  int b = idx >= 8000;
  int tt = idx - b * 8000;
  int l0 = tt >> 3, j0 = tt & 7;
  float v = 0.f;
  if (l0 <= LQ - 1) v += Z[(size_t)(b * 1008 + l0) * 16 + j0];
  if (l0 >= 1) v += Z[(size_t)(b * 1008 + l0 - 1) * 16 + j0 + 8];
  out[idx] = v;
}

// ==================== launch ====================
extern "C" void kernel_launch(void* const* d_in, const int* in_sizes, int n_in,
                              void* d_out, int out_size, void* d_ws, size_t ws_size,
                              hipStream_t stream) {
  const float* mixture = (const float*)d_in[0];
  const float* enc_w = (const float*)d_in[1];
  const float* dec_w = (const float*)d_in[2];
  const float* gn_w = (const float*)d_in[3];
  const float* gn_b = (const float*)d_in[4];
  const float* bot_w = (const float*)d_in[5];
  const float* bot_b = (const float*)d_in[6];
  const float* blk_norm_w = (const float*)d_in[7];
  const float* in_w = (const float*)d_in[8];
  const float* conv_w = (const float*)d_in[9];
  const float* conv_b = (const float*)d_in[10];
  const float* xproj_w = (const float*)d_in[11];
  const float* dt_w = (const float*)d_in[12];
  const float* dt_b = (const float*)d_in[13];
  const float* A_log = (const float*)d_in[14];
  const float* Dmat = (const float*)d_in[15];
  const float* out_w = (const float*)d_in[16];
  const float* normf_w = (const float*)d_in[17];
  const float* mask_w = (const float*)d_in[18];
  const float* mask_b = (const float*)d_in[19];
  float* outp = (float*)d_out;

  float* W = (float*)d_ws;
  size_t off = 0;
  auto alloc = [&](size_t n) {
    float* p = W + off;
    off += (n + 255) & ~(size_t)255;
    return p;
  };
  float* stats = alloc(8);
  float* w2 = alloc(65536);
  float* cc = alloc(512);
  float* mw = alloc(511488);          // [b][n][l]
  float* x = alloc(511488);           // [bl][256]
  float* xn = alloc(511488);          // fp32 (final rms only)
  float* xzb = alloc(4091904);        // [bl][2048]
  float* xcb = alloc(2045952);        // [dir][bl][512]
  float* xdblb = alloc(191808);       // [dir][bl][48]
  float* dtgb = alloc(2045952);       // [dir][bl][512]
  float* maskedb = alloc(511488);     // masked_t [bl][256]
  float* prodb = alloc(524288);
  float* locb = alloc(524288);
  float* zbuf = alloc(32256);         // [2][1008][16]
  float* dtwt = alloc(131072);        // transposed dt weights
  ushort* xnh = (ushort*)alloc(255744);   // bf16 [bl][256]
  ushort* ghb = (ushort*)alloc(1022976);  // bf16 [dir][bl][512]
  ushort* inwh = (ushort*)alloc(2097152); // bf16 in_w (all 8 blocks)
  ushort* outwh = (ushort*)alloc(1048576);// bf16 out_w

  k_quant<<<16384, 256, 0, stream>>>(in_w, out_w, dt_w, inwh, outwh, dtwt);
  hipMemsetAsync(stats, 0, 32, stream);
  k_enc<<<1998, 256, 0, stream>>>(mixture, enc_w, mw, stats);
  k_stats<<<1, 64, 0, stream>>>(stats);
  k_prep<<<256, 256, 0, stream>>>(bot_w, gn_w, gn_b, bot_b, stats, w2, cc);
  gemm64<0><<<dim3(32, 4, 1), 256, 0, stream>>>(mw, w2, x, stats, cc, BLQ, 256, 0, 0, 0);

  for (int i = 0; i < 8; ++i) {
    k_rms<true><<<500, 256, 0, stream>>>(x, blk_norm_w + i * 256, nullptr, xnh);
    k_mm1<<<dim3(16, 16), 256, 0, stream>>>(xnh, inwh + (size_t)i * 524288, xzb);
    k_conv<<<dim3(3996, 2, 1), 256, 0, stream>>>(xzb, conv_w, conv_b, xcb, i);
    gemm64<4><<<dim3(32, 1, 2), 256, 0, stream>>>(
        xcb, xproj_w + (size_t)i * 2 * 48 * 512, xdblb, nullptr, nullptr, BLQ, 512,
        BLQ * 512, 48 * 512, BLQ * 48);
    k_dt<<<dim3(3996, 2, 1), 256, 0, stream>>>(xdblb, dtwt, dt_b, dtgb, i);
    k_scanA<<<1024, 256, 0, stream>>>(dtgb, xcb, xdblb, A_log, prodb, locb, i);
    k_scanC<<<1024, 256, 0, stream>>>(dtgb, xcb, xdblb, xzb, A_log, Dmat, prodb, locb, ghb, i);
    k_mm2<<<dim3(16, 2), 256, 0, stream>>>(ghb, outwh + (size_t)i * 262144, x);
  }

  k_rms<false><<<500, 256, 0, stream>>>(x, normf_w, xn, nullptr);
  gemm64<3><<<dim3(32, 4, 1), 256, 0, stream>>>(xn, mask_w, maskedb, mask_b, mw, BLQ, 256, 0, 0, 0);
  k_zg<<<126, 256, 0, stream>>>(maskedb, dec_w, zbuf);
  k_comb<<<63, 256, 0, stream>>>(zbuf, outp);
}